// Round 1
// baseline (5319.197 us; speedup 1.0000x reference)
//
#include <hip/hip_runtime.h>
#include <hip/hip_bf16.h>
#include <stdint.h>

#define BB 4
#define TT 100
#define DD 256
#define LL 256
#define NF (BB*TT)          // 400 frames
#define FRAME (DD*LL)       // 65536 elements per frame (ch * spatial)
#define EPSB 1e-5f

__device__ __forceinline__ float bf2f(unsigned short u){
    return __uint_as_float(((unsigned int)u) << 16);
}
__device__ __forceinline__ unsigned short f2bf(float f){
    __hip_bfloat16 h = __float2bfloat16(f);
    return *reinterpret_cast<unsigned short*>(&h);
}
__device__ __forceinline__ float sigm(float x){ return 1.0f/(1.0f+expf(-x)); }

// ---------------- K0: reorder conv weights OIHW -> [i][o][tap] ----------------
__global__ void k_reorder_w(const float* __restrict__ cw, float* __restrict__ wr){
    int idx = blockIdx.x*256 + threadIdx.x;
    if (idx >= 256*256*9) return;
    int t9 = idx % 9;
    int rest = idx / 9;
    int i = rest & 255;
    int o = rest >> 8;
    wr[(((i<<8)+o)*9) + t9] = cw[idx];
}

// ---------------- K1: conv3x3 SAME + bias, fp32 math, bf16 store ----------------
// grid (8, 400): blockIdx.x = oc group (32 oc), blockIdx.y = frame. 256 threads (one spatial pos each).
__global__ __launch_bounds__(256) void k_conv(const float* __restrict__ x,
                                              const float* __restrict__ wr,
                                              const float* __restrict__ cb,
                                              unsigned short* __restrict__ y){
    const int f   = blockIdx.y;
    const int oc0 = blockIdx.x * 32;
    const int tid = threadIdx.x;
    const int h = tid >> 4, w = tid & 15;
    __shared__ float ldsX[32*324];           // 32 ch x 18x18 padded tile
    float acc[32];
#pragma unroll
    for (int oc=0; oc<32; ++oc) acc[oc] = cb[oc0+oc];
    const float4* x4 = (const float4*)x;
    for (int chunk=0; chunk<8; ++chunk){
        __syncthreads();
        for (int i=tid; i<32*324; i+=256) ldsX[i]=0.f;
        __syncthreads();
        for (int icl = tid>>6; icl<32; icl+=4){
            int lane = tid & 63;
            float4 v = x4[((size_t)f*256 + chunk*32 + icl)*64 + lane];
            int hh = lane>>2, ww2 = (lane&3)*4;
            float* p = &ldsX[icl*324 + (hh+1)*18 + (ww2+1)];
            p[0]=v.x; p[1]=v.y; p[2]=v.z; p[3]=v.w;
        }
        __syncthreads();
        for (int icl=0; icl<32; ++icl){
            const float* xp = &ldsX[icl*324 + h*18 + w];
            float xv[9];
#pragma unroll
            for (int r=0;r<3;++r)
#pragma unroll
                for (int c=0;c<3;++c) xv[r*3+c]=xp[r*18+c];
            const float* wp = &wr[((((chunk*32+icl)<<8) + oc0)*9)];  // wave-uniform -> scalar loads
#pragma unroll
            for (int oc=0;oc<32;++oc){
                float a = acc[oc];
#pragma unroll
                for (int t9=0;t9<9;++t9) a = fmaf(xv[t9], wp[oc*9+t9], a);
                acc[oc]=a;
            }
        }
    }
#pragma unroll
    for (int oc=0;oc<32;++oc){
        y[((size_t)f*256 + oc0+oc)*256 + tid] = f2bf(acc[oc]);
    }
}

// ---------------- K2: BN batch stats -> scale/shift per channel ----------------
__global__ __launch_bounds__(256) void k_bnstats(const unsigned short* __restrict__ y,
                                                 const float* __restrict__ gamma,
                                                 const float* __restrict__ beta,
                                                 float* __restrict__ scale,
                                                 float* __restrict__ shift){
    const int c = blockIdx.x, tid = threadIdx.x;
    float s=0.f, q=0.f;
    for (int f=0; f<NF; ++f){
        float v = bf2f(y[(size_t)f*FRAME + c*256 + tid]);
        s += v; q += v*v;
    }
    __shared__ float rs[4], rq[4];
    int lane = tid&63, wave = tid>>6;
#pragma unroll
    for (int off=32; off; off>>=1){ s += __shfl_down(s,off,64); q += __shfl_down(q,off,64); }
    if (lane==0){ rs[wave]=s; rq[wave]=q; }
    __syncthreads();
    if (tid==0){
        s = rs[0]+rs[1]+rs[2]+rs[3];
        q = rq[0]+rq[1]+rq[2]+rq[3];
        const float invN = 1.0f/(float)(NF*256);
        float mean = s*invN;
        float var  = q*invN - mean*mean;
        float istd = rsqrtf(var + EPSB);
        float sc = gamma[c]*istd;
        scale[c] = sc;
        shift[c] = beta[c] - mean*sc;
    }
}

// ---------------- K3: per-frame fdot -> softmax -> alpha/logp out, ctx_f, x0 ----------------
// grid 400 blocks x 256 threads
__global__ __launch_bounds__(256) void k_frame(const unsigned short* __restrict__ y,
                                               const float* __restrict__ scale,
                                               const float* __restrict__ shift,
                                               const float* __restrict__ wattn,
                                               float* __restrict__ d_out,
                                               float* __restrict__ ctx_f,
                                               float* __restrict__ x0g){
    const int f = blockIdx.x, tid = threadIdx.x;
    const int b = f / TT, t = f - b*TT;
    const int wave = tid>>6, lane = tid&63;
    __shared__ float fdotL[256], alphaL[256], x0acc[256], wattnL[256];
    __shared__ float redM[4], redS[4];
    wattnL[tid] = wattn[tid];
    x0acc[tid] = 0.f;
    __syncthreads();
    const bool isT0 = (t==0);
    const float wl0 = wattnL[lane*4+0], wl1 = wattnL[lane*4+1];
    const float wl2 = wattnL[lane*4+2], wl3 = wattnL[lane*4+3];
    const ushort4* y4 = (const ushort4*)(y + (size_t)f*FRAME);
    for (int ci=0; ci<64; ++ci){
        int c = wave + ci*4;
        ushort4 u = y4[c*64 + lane];
        float sc = scale[c], sh = shift[c];
        float v0 = fmaxf(fmaf(bf2f(u.x),sc,sh),0.f);
        float v1 = fmaxf(fmaf(bf2f(u.y),sc,sh),0.f);
        float v2 = fmaxf(fmaf(bf2f(u.z),sc,sh),0.f);
        float v3 = fmaxf(fmaf(bf2f(u.w),sc,sh),0.f);
        float s = v0*wl0 + v1*wl1 + v2*wl2 + v3*wl3;
#pragma unroll
        for (int off=32; off; off>>=1) s += __shfl_down(s,off,64);
        if (lane==0) fdotL[c] = s;
        if (isT0){
            atomicAdd(&x0acc[lane*4+0], v0);
            atomicAdd(&x0acc[lane*4+1], v1);
            atomicAdd(&x0acc[lane*4+2], v2);
            atomicAdd(&x0acc[lane*4+3], v3);
        }
    }
    __syncthreads();
    // softmax over 256 channel logits (shift-invariant: proj/wattn_b terms drop out)
    float v = fdotL[tid];
    float m = v;
#pragma unroll
    for (int off=32; off; off>>=1) m = fmaxf(m, __shfl_down(m,off,64));
    if (lane==0) redM[wave]=m;
    __syncthreads();
    m = fmaxf(fmaxf(redM[0],redM[1]),fmaxf(redM[2],redM[3]));
    float e = expf(v-m);
    float ss = e;
#pragma unroll
    for (int off=32; off; off>>=1) ss += __shfl_down(ss,off,64);
    if (lane==0) redS[wave]=ss;
    __syncthreads();
    float S = redS[0]+redS[1]+redS[2]+redS[3];
    float logS = logf(S);
    float alpha = e / S;
    d_out[800    + ((t*BB)+b)*256 + tid] = alpha;
    d_out[103200 + ((t*BB)+b)*256 + tid] = v - m - logS;
    alphaL[tid] = alpha;
    if (isT0) x0g[b*256+tid] = x0acc[tid];   // channel-sum; /256 applied in k_init
    __syncthreads();
    // ctx_f[f, d2] = sum_l feats[l,d2] * alpha[l]
    const unsigned short* yf = y + (size_t)f*FRAME;
    float ctx = 0.f;
    for (int c=0;c<256;++c){
        float yv = fmaxf(fmaf(bf2f(yf[c*256+tid]), scale[c], shift[c]), 0.f);
        ctx = fmaf(yv, alphaL[c], ctx);
    }
    ctx_f[f*256+tid] = ctx;
}

// ---------------- K4: Gperm[t,b,col] = ctx_f[f] . wih[r], gate-permuted ----------------
__global__ __launch_bounds__(256) void k_gperm(const float* __restrict__ ctx_f,
                                               const float* __restrict__ wih,
                                               float* __restrict__ Gperm){
    const int f = blockIdx.x, tid = threadIdx.x;
    const int b = f / TT, t = f - b*TT;
    __shared__ float ctxL[256];
    ctxL[tid] = ctx_f[f*256+tid];
    __syncthreads();
    const int wave = tid>>6, lane = tid&63;
    const float4* c4 = (const float4*)ctxL;
    float4 cv = c4[lane];
    const float4* w4 = (const float4*)wih;
    float* gout = Gperm + ((size_t)(t*BB)+b)*1024;
    for (int r=wave; r<1024; r+=4){
        float4 wv = w4[r*64 + lane];
        float s = cv.x*wv.x + cv.y*wv.y + cv.z*wv.z + cv.w*wv.w;
#pragma unroll
        for (int off=32; off; off>>=1) s += __shfl_down(s,off,64);
        if (lane==0){
            int g = r>>8, k = r&255, kc = k>>5, u = k&31;
            gout[kc*128 + g*32 + u] = s;
        }
    }
}

// ---------------- K5: W_comb = whh + wih@w_w, transposed+permuted; bias_comb ----------------
__global__ __launch_bounds__(256) void k_wcomb(const float* __restrict__ wih,
                                               const float* __restrict__ whh,
                                               const float* __restrict__ ww,
                                               const float* __restrict__ wb,
                                               const float* __restrict__ bih,
                                               const float* __restrict__ bhh,
                                               float* __restrict__ WpermT,
                                               float* __restrict__ biasperm){
    const int r = blockIdx.x, tid = threadIdx.x;
    __shared__ float wihL[256];
    wihL[tid] = wih[r*256+tid];
    __syncthreads();
    float acc = whh[r*256+tid];
    for (int k=0;k<256;++k) acc = fmaf(wihL[k], ww[k*256+tid], acc);
    int g = r>>8, kk = r&255, kc = kk>>5, u = kk&31;
    int col = kc*128 + g*32 + u;
    WpermT[tid*1024 + col] = acc;
    if (tid < 64){
        float s = 0.f;
#pragma unroll
        for (int q=0;q<4;++q) s += wihL[tid + 64*q] * wb[tid + 64*q];
#pragma unroll
        for (int off=32; off; off>>=1) s += __shfl_down(s,off,64);
        if (tid==0) biasperm[col] = bih[r] + bhh[r] + s;
    }
}

// ---------------- K6: initial hx/cx = tanh(x0 @ W.T + b) ----------------
// grid 8: blockIdx = b*2 + which (0=h, 1=c)
__global__ __launch_bounds__(256) void k_init(const float* __restrict__ x0g,
                                              const float* __restrict__ ihw,
                                              const float* __restrict__ ihb,
                                              const float* __restrict__ icw,
                                              const float* __restrict__ icb,
                                              float* __restrict__ hx0,
                                              float* __restrict__ cx){
    const int b = blockIdx.x >> 1, which = blockIdx.x & 1;
    const int tid = threadIdx.x, wave = tid>>6, lane = tid&63;
    __shared__ float xL[256];
    xL[tid] = x0g[b*256+tid] * (1.0f/256.0f);
    __syncthreads();
    const float* wmat = which ? icw : ihw;
    const float* bias = which ? icb : ihb;
    float* dst = which ? cx : hx0;
    const float4* x4 = (const float4*)xL;
    float4 xv = x4[lane];
    const float4* w4 = (const float4*)wmat;
    for (int r=wave; r<256; r+=4){
        float4 wv = w4[r*64+lane];
        float s = xv.x*wv.x + xv.y*wv.y + xv.z*wv.z + xv.w*wv.w;
#pragma unroll
        for (int off=32; off; off>>=1) s += __shfl_down(s,off,64);
        if (lane==0) dst[b*256+r] = tanhf(s + bias[r]);
    }
}

// ---------------- K7: one LSTM step (32 blocks = 4 b x 8 kc, 128 threads) ----------------
__global__ __launch_bounds__(128) void k_step(int t,
                                              const float* __restrict__ Gperm,
                                              const float* __restrict__ WpermT,
                                              const float* __restrict__ biasperm,
                                              const float* __restrict__ hxA,
                                              float* __restrict__ hxB,
                                              float* __restrict__ cx,
                                              const float* __restrict__ woutw,
                                              const float* __restrict__ woutb,
                                              float* __restrict__ preds){
    const int b = blockIdx.x >> 3, kc = blockIdx.x & 7;
    const int tid = threadIdx.x;
    __shared__ float hxL[256], gL[128];
    hxL[tid]     = hxA[b*256+tid];
    hxL[tid+128] = hxA[b*256+tid+128];
    __syncthreads();
    if (kc==0 && t>0){
        const int wave = tid>>6, lane=tid&63;
        const float4* w4 = (const float4*)(woutw + wave*256);
        const float4* h4 = (const float4*)hxL;
        float4 a = h4[lane], wv = w4[lane];
        float s = a.x*wv.x + a.y*wv.y + a.z*wv.z + a.w*wv.w;
#pragma unroll
        for (int off=32; off; off>>=1) s += __shfl_down(s,off,64);
        if (lane==0) preds[(t-1)*8 + b*2 + wave] = s + woutb[wave];
    }
    const int col = kc*128 + tid;
    float acc = Gperm[((size_t)(t*BB)+b)*1024 + col] + biasperm[col];
    const float* wp = WpermT + col;
#pragma unroll 8
    for (int d=0; d<256; ++d) acc = fmaf(hxL[d], wp[(size_t)d*1024], acc);
    gL[tid] = acc;
    __syncthreads();
    if (tid < 32){
        const int k = kc*32 + tid;
        float ig = gL[tid], fg = gL[32+tid], gg = gL[64+tid], og = gL[96+tid];
        float cn = sigm(fg)*cx[b*256+k] + sigm(ig)*tanhf(gg);
        float hn = sigm(og)*tanhf(cn);
        cx[b*256+k]  = cn;
        hxB[b*256+k] = hn;
    }
}

// ---------------- K8: final pred (t=99) ----------------
__global__ __launch_bounds__(128) void k_predfinal(const float* __restrict__ hx,
                                                   const float* __restrict__ woutw,
                                                   const float* __restrict__ woutb,
                                                   float* __restrict__ preds){
    const int b = blockIdx.x;
    const int tid = threadIdx.x, wave = tid>>6, lane = tid&63;
    __shared__ float hxL[256];
    hxL[tid] = hx[b*256+tid]; hxL[tid+128] = hx[b*256+tid+128];
    __syncthreads();
    const float4* w4 = (const float4*)(woutw + wave*256);
    const float4* h4 = (const float4*)hxL;
    float4 a = h4[lane], wv = w4[lane];
    float s = a.x*wv.x + a.y*wv.y + a.z*wv.z + a.w*wv.w;
#pragma unroll
    for (int off=32; off; off>>=1) s += __shfl_down(s,off,64);
    if (lane==0) preds[99*8 + b*2 + wave] = s + woutb[wave];
}

extern "C" void kernel_launch(void* const* d_in, const int* in_sizes, int n_in,
                              void* d_out, int out_size, void* d_ws, size_t ws_size,
                              hipStream_t stream){
    const float* cam   = (const float*)d_in[0];
    const float* convw = (const float*)d_in[1];
    const float* convb = (const float*)d_in[2];
    const float* gamma = (const float*)d_in[3];
    const float* beta  = (const float*)d_in[4];
    const float* ihw   = (const float*)d_in[5];
    const float* ihb   = (const float*)d_in[6];
    const float* icw   = (const float*)d_in[7];
    const float* icb   = (const float*)d_in[8];
    const float* ww    = (const float*)d_in[9];
    const float* wb    = (const float*)d_in[10];
    const float* wattn = (const float*)d_in[11];
    // d_in[12] = wattn_b: unused (softmax is shift-invariant)
    const float* wih   = (const float*)d_in[13];
    const float* whh   = (const float*)d_in[14];
    const float* bih   = (const float*)d_in[15];
    const float* bhh   = (const float*)d_in[16];
    const float* woutw = (const float*)d_in[17];
    const float* woutb = (const float*)d_in[18];
    float* out = (float*)d_out;

    char* wsb = (char*)d_ws;
    size_t off = 0;
    auto alloc = [&](size_t bytes)->void*{
        void* p = wsb + off; off += (bytes + 255) & ~(size_t)255; return p;
    };
    unsigned short* y   = (unsigned short*)alloc((size_t)NF*FRAME*2);
    float* wr       = (float*)alloc((size_t)589824*4);
    float* scale    = (float*)alloc(256*4);
    float* shift    = (float*)alloc(256*4);
    float* x0g      = (float*)alloc(1024*4);
    float* ctx_f    = (float*)alloc((size_t)NF*256*4);
    float* Gperm    = (float*)alloc((size_t)NF*1024*4);
    float* WpermT   = (float*)alloc((size_t)262144*4);
    float* biasperm = (float*)alloc(1024*4);
    float* hx0      = (float*)alloc(1024*4);
    float* hx1      = (float*)alloc(1024*4);
    float* cx       = (float*)alloc(1024*4);

    hipLaunchKernelGGL(k_reorder_w, dim3(2304), dim3(256), 0, stream, convw, wr);
    hipLaunchKernelGGL(k_conv, dim3(8, NF), dim3(256), 0, stream, cam, wr, convb, y);
    hipLaunchKernelGGL(k_bnstats, dim3(256), dim3(256), 0, stream, y, gamma, beta, scale, shift);
    hipLaunchKernelGGL(k_frame, dim3(NF), dim3(256), 0, stream, y, scale, shift, wattn, out, ctx_f, x0g);
    hipLaunchKernelGGL(k_wcomb, dim3(1024), dim3(256), 0, stream, wih, whh, ww, wb, bih, bhh, WpermT, biasperm);
    hipLaunchKernelGGL(k_gperm, dim3(NF), dim3(256), 0, stream, ctx_f, wih, Gperm);
    hipLaunchKernelGGL(k_init, dim3(8), dim3(256), 0, stream, x0g, ihw, ihb, icw, icb, hx0, cx);
    for (int t=0; t<TT; ++t){
        float* hA = (t&1)? hx1 : hx0;
        float* hB = (t&1)? hx0 : hx1;
        hipLaunchKernelGGL(k_step, dim3(32), dim3(128), 0, stream, t,
                           Gperm, WpermT, biasperm, hA, hB, cx, woutw, woutb, out);
    }
    hipLaunchKernelGGL(k_predfinal, dim3(4), dim3(128), 0, stream, hx0, woutw, woutb, out);
}

// Round 2
// 1498.930 us; speedup vs baseline: 3.5487x; 3.5487x over previous
//
#include <hip/hip_runtime.h>
#include <hip/hip_bf16.h>
#include <stdint.h>

#define BB 4
#define TT 100
#define DD 256
#define LL 256
#define NF (BB*TT)          // 400 frames
#define FRAME (DD*LL)       // 65536 elements per frame (ch * spatial)
#define EPSB 1e-5f

typedef __bf16  bf16x8 __attribute__((ext_vector_type(8)));
typedef float   f32x4  __attribute__((ext_vector_type(4)));

__device__ __forceinline__ float bf2f(unsigned short u){
    return __uint_as_float(((unsigned int)u) << 16);
}
__device__ __forceinline__ unsigned short f2bf(float f){
    __hip_bfloat16 h = __float2bfloat16(f);
    return *reinterpret_cast<unsigned short*>(&h);
}
__device__ __forceinline__ float sigm(float x){ return 1.0f/(1.0f+expf(-x)); }

// ---------------- K0: reorder conv weights OIHW fp32 -> Wr2[tap][oc][ic] bf16 ----------------
__global__ void k_reorder2(const float* __restrict__ cw, unsigned short* __restrict__ wr){
    int idx = blockIdx.x*256 + threadIdx.x;          // 589824 total
    if (idx >= 256*256*9) return;
    int i  = idx & 255;
    int rest = idx >> 8;
    int o  = rest & 255;
    int t9 = rest >> 8;
    wr[idx] = f2bf(cw[((o<<8) + i)*9 + t9]);
}

// ---------------- K1: conv3x3 SAME + bias via MFMA implicit GEMM, bf16 y ----------------
// grid (4, 400): x = oc group (64 oc), y = frame. 256 threads = 4 waves.
// LDS X: [324 padded spatial][32 ic], stride 40 ushorts (80B, 16B-aligned rows).
// LDS A: [3 taps][64 oc][32 ic], stride 40.
#define XSTR 40
__global__ __launch_bounds__(256, 3) void k_conv2(const float* __restrict__ cam,
                                                  const unsigned short* __restrict__ wr,
                                                  const float* __restrict__ cb,
                                                  unsigned short* __restrict__ y){
    const int f   = blockIdx.y;
    const int oc0 = blockIdx.x * 64;
    const int tid = threadIdx.x;
    const int wv    = tid >> 6;          // wave 0..3 -> h rows wv*4..wv*4+3
    const int quad  = (tid >> 4) & 3;    // k-group / row-group within wave
    const int wlane = tid & 15;

    __shared__ __align__(16) unsigned short Xl[324*XSTR];   // 25920 B
    __shared__ __align__(16) unsigned short Al[192*XSTR];   // 15360 B

    // zero entire X tile once (borders stay zero; interior rewritten each chunk)
    for (int i = tid; i < 324*XSTR/2; i += 256) ((unsigned int*)Xl)[i] = 0u;

    // accumulators init with bias: D row = quad*4 + reg
    f32x4 acc[4][4];
#pragma unroll
    for (int mt=0; mt<4; ++mt){
        const int oc = oc0 + mt*16 + quad*4;
        f32x4 bv; bv[0]=cb[oc]; bv[1]=cb[oc+1]; bv[2]=cb[oc+2]; bv[3]=cb[oc+3];
#pragma unroll
        for (int nt=0; nt<4; ++nt) acc[mt][nt] = bv;
    }

    // spatial position owned by this thread for X staging
    const int sp  = tid;                  // p = 0..255
    const int spp = ((sp>>4)+1)*18 + (sp&15) + 1;   // padded index
    const float* xs = cam + ((size_t)f*256)*256 + sp;

    for (int ck=0; ck<8; ++ck){
        const int c0 = ck*32;
        for (int tg=0; tg<3; ++tg){       // tg == kernel row r; inner cc == kernel col
            __syncthreads();              // prev compute done -> safe to overwrite LDS
            if (tg == 0){
                // stage X chunk: thread owns spatial p, gathers 32 ic (coalesced dword loads)
                const float* xc = xs + (size_t)c0*256;
#pragma unroll
                for (int jb=0; jb<4; ++jb){
                    unsigned int q0,q1,q2,q3;
                    {
                        float a0=xc[(jb*8+0)*256], a1=xc[(jb*8+1)*256];
                        float a2=xc[(jb*8+2)*256], a3=xc[(jb*8+3)*256];
                        float a4=xc[(jb*8+4)*256], a5=xc[(jb*8+5)*256];
                        float a6=xc[(jb*8+6)*256], a7=xc[(jb*8+7)*256];
                        q0 = (unsigned int)f2bf(a0) | ((unsigned int)f2bf(a1)<<16);
                        q1 = (unsigned int)f2bf(a2) | ((unsigned int)f2bf(a3)<<16);
                        q2 = (unsigned int)f2bf(a4) | ((unsigned int)f2bf(a5)<<16);
                        q3 = (unsigned int)f2bf(a6) | ((unsigned int)f2bf(a7)<<16);
                    }
                    uint4 qv; qv.x=q0; qv.y=q1; qv.z=q2; qv.w=q3;
                    *(uint4*)&Xl[spp*XSTR + jb*8] = qv;     // ds_write_b128, <=2-way banks
                }
            }
            // stage A for 3 taps of this row: rows (cc,oc_l) = tid
            if (tid < 192){
                const unsigned short* src = wr +
                    ((size_t)((tg*3 + (tid>>6))*256 + oc0 + (tid&63)))*256 + c0;
                const uint4* s4 = (const uint4*)src;
                uint4* dq = (uint4*)(Al + tid*XSTR);
                dq[0]=s4[0]; dq[1]=s4[1]; dq[2]=s4[2]; dq[3]=s4[3];
            }
            __syncthreads();
#pragma unroll
            for (int cc=0; cc<3; ++cc){
                bf16x8 af[4], bfr[4];
#pragma unroll
                for (int mt=0; mt<4; ++mt)
                    af[mt] = *(const bf16x8*)(Al + ((cc*64 + mt*16 + wlane)*XSTR + quad*8));
#pragma unroll
                for (int nt=0; nt<4; ++nt){
                    const int hh = wv*4 + nt;
                    const int pp = (hh + tg)*18 + wlane + cc;
                    bfr[nt] = *(const bf16x8*)(Xl + (pp*XSTR + quad*8));
                }
#pragma unroll
                for (int mt=0; mt<4; ++mt)
#pragma unroll
                    for (int nt=0; nt<4; ++nt)
                        acc[mt][nt] = __builtin_amdgcn_mfma_f32_16x16x32_bf16(
                            af[mt], bfr[nt], acc[mt][nt], 0, 0, 0);
            }
        }
    }

    // epilogue: C/D layout col=lane&15, row=(lane>>4)*4+reg  [m89-verified]
#pragma unroll
    for (int mt=0; mt<4; ++mt){
        const int oc = oc0 + mt*16 + quad*4;
#pragma unroll
        for (int nt=0; nt<4; ++nt){
            const int p = (wv*4 + nt)*16 + wlane;
#pragma unroll
            for (int reg=0; reg<4; ++reg)
                y[((size_t)(f*256) + oc + reg)*256 + p] = f2bf(acc[mt][nt][reg]);
        }
    }
}

// ---------------- K2: BN batch stats -> scale/shift per channel ----------------
__global__ __launch_bounds__(256) void k_bnstats(const unsigned short* __restrict__ y,
                                                 const float* __restrict__ gamma,
                                                 const float* __restrict__ beta,
                                                 float* __restrict__ scale,
                                                 float* __restrict__ shift){
    const int c = blockIdx.x, tid = threadIdx.x;
    float s=0.f, q=0.f;
    for (int f=0; f<NF; ++f){
        float v = bf2f(y[(size_t)f*FRAME + c*256 + tid]);
        s += v; q += v*v;
    }
    __shared__ float rs[4], rq[4];
    int lane = tid&63, wave = tid>>6;
#pragma unroll
    for (int off=32; off; off>>=1){ s += __shfl_down(s,off,64); q += __shfl_down(q,off,64); }
    if (lane==0){ rs[wave]=s; rq[wave]=q; }
    __syncthreads();
    if (tid==0){
        s = rs[0]+rs[1]+rs[2]+rs[3];
        q = rq[0]+rq[1]+rq[2]+rq[3];
        const float invN = 1.0f/(float)(NF*256);
        float mean = s*invN;
        float var  = q*invN - mean*mean;
        float istd = rsqrtf(var + EPSB);
        float sc = gamma[c]*istd;
        scale[c] = sc;
        shift[c] = beta[c] - mean*sc;
    }
}

// ---------------- K3: per-frame fdot -> softmax -> alpha/logp out, ctx_f, x0 ----------------
__global__ __launch_bounds__(256) void k_frame(const unsigned short* __restrict__ y,
                                               const float* __restrict__ scale,
                                               const float* __restrict__ shift,
                                               const float* __restrict__ wattn,
                                               float* __restrict__ d_out,
                                               float* __restrict__ ctx_f,
                                               float* __restrict__ x0g){
    const int f = blockIdx.x, tid = threadIdx.x;
    const int b = f / TT, t = f - b*TT;
    const int wave = tid>>6, lane = tid&63;
    __shared__ float fdotL[256], alphaL[256], x0acc[256], wattnL[256];
    __shared__ float redM[4], redS[4];
    wattnL[tid] = wattn[tid];
    x0acc[tid] = 0.f;
    __syncthreads();
    const bool isT0 = (t==0);
    const float wl0 = wattnL[lane*4+0], wl1 = wattnL[lane*4+1];
    const float wl2 = wattnL[lane*4+2], wl3 = wattnL[lane*4+3];
    const ushort4* y4 = (const ushort4*)(y + (size_t)f*FRAME);
    for (int ci=0; ci<64; ++ci){
        int c = wave + ci*4;
        ushort4 u = y4[c*64 + lane];
        float sc = scale[c], sh = shift[c];
        float v0 = fmaxf(fmaf(bf2f(u.x),sc,sh),0.f);
        float v1 = fmaxf(fmaf(bf2f(u.y),sc,sh),0.f);
        float v2 = fmaxf(fmaf(bf2f(u.z),sc,sh),0.f);
        float v3 = fmaxf(fmaf(bf2f(u.w),sc,sh),0.f);
        float s = v0*wl0 + v1*wl1 + v2*wl2 + v3*wl3;
#pragma unroll
        for (int off=32; off; off>>=1) s += __shfl_down(s,off,64);
        if (lane==0) fdotL[c] = s;
        if (isT0){
            atomicAdd(&x0acc[lane*4+0], v0);
            atomicAdd(&x0acc[lane*4+1], v1);
            atomicAdd(&x0acc[lane*4+2], v2);
            atomicAdd(&x0acc[lane*4+3], v3);
        }
    }
    __syncthreads();
    float v = fdotL[tid];
    float m = v;
#pragma unroll
    for (int off=32; off; off>>=1) m = fmaxf(m, __shfl_down(m,off,64));
    if (lane==0) redM[wave]=m;
    __syncthreads();
    m = fmaxf(fmaxf(redM[0],redM[1]),fmaxf(redM[2],redM[3]));
    float e = expf(v-m);
    float ss = e;
#pragma unroll
    for (int off=32; off; off>>=1) ss += __shfl_down(ss,off,64);
    if (lane==0) redS[wave]=ss;
    __syncthreads();
    float S = redS[0]+redS[1]+redS[2]+redS[3];
    float logS = logf(S);
    float alpha = e / S;
    d_out[800    + ((t*BB)+b)*256 + tid] = alpha;
    d_out[103200 + ((t*BB)+b)*256 + tid] = v - m - logS;
    alphaL[tid] = alpha;
    if (isT0) x0g[b*256+tid] = x0acc[tid];
    __syncthreads();
    const unsigned short* yf = y + (size_t)f*FRAME;
    float ctx = 0.f;
    for (int c=0;c<256;++c){
        float yv = fmaxf(fmaf(bf2f(yf[c*256+tid]), scale[c], shift[c]), 0.f);
        ctx = fmaf(yv, alphaL[c], ctx);
    }
    ctx_f[f*256+tid] = ctx;
}

// ---------------- K4: Gperm[t,b,col] = ctx_f[f] . wih[r], gate-permuted ----------------
__global__ __launch_bounds__(256) void k_gperm(const float* __restrict__ ctx_f,
                                               const float* __restrict__ wih,
                                               float* __restrict__ Gperm){
    const int f = blockIdx.x, tid = threadIdx.x;
    const int b = f / TT, t = f - b*TT;
    __shared__ float ctxL[256];
    ctxL[tid] = ctx_f[f*256+tid];
    __syncthreads();
    const int wave = tid>>6, lane = tid&63;
    const float4* c4 = (const float4*)ctxL;
    float4 cv = c4[lane];
    const float4* w4 = (const float4*)wih;
    float* gout = Gperm + ((size_t)(t*BB)+b)*1024;
    for (int r=wave; r<1024; r+=4){
        float4 wv = w4[r*64 + lane];
        float s = cv.x*wv.x + cv.y*wv.y + cv.z*wv.z + cv.w*wv.w;
#pragma unroll
        for (int off=32; off; off>>=1) s += __shfl_down(s,off,64);
        if (lane==0){
            int g = r>>8, k = r&255, kc = k>>5, u = k&31;
            gout[kc*128 + g*32 + u] = s;
        }
    }
}

// ---------------- K5: W_comb = whh + wih@w_w, transposed+permuted; bias_comb ----------------
__global__ __launch_bounds__(256) void k_wcomb(const float* __restrict__ wih,
                                               const float* __restrict__ whh,
                                               const float* __restrict__ ww,
                                               const float* __restrict__ wb,
                                               const float* __restrict__ bih,
                                               const float* __restrict__ bhh,
                                               float* __restrict__ WpermT,
                                               float* __restrict__ biasperm){
    const int r = blockIdx.x, tid = threadIdx.x;
    __shared__ float wihL[256];
    wihL[tid] = wih[r*256+tid];
    __syncthreads();
    float acc = whh[r*256+tid];
    for (int k=0;k<256;++k) acc = fmaf(wihL[k], ww[k*256+tid], acc);
    int g = r>>8, kk = r&255, kc = kk>>5, u = kk&31;
    int col = kc*128 + g*32 + u;
    WpermT[tid*1024 + col] = acc;
    if (tid < 64){
        float s = 0.f;
#pragma unroll
        for (int q=0;q<4;++q) s += wihL[tid + 64*q] * wb[tid + 64*q];
#pragma unroll
        for (int off=32; off; off>>=1) s += __shfl_down(s,off,64);
        if (tid==0) biasperm[col] = bih[r] + bhh[r] + s;
    }
}

// ---------------- K6: initial hx/cx = tanh(x0 @ W.T + b) ----------------
__global__ __launch_bounds__(256) void k_init(const float* __restrict__ x0g,
                                              const float* __restrict__ ihw,
                                              const float* __restrict__ ihb,
                                              const float* __restrict__ icw,
                                              const float* __restrict__ icb,
                                              float* __restrict__ hx0,
                                              float* __restrict__ cx){
    const int b = blockIdx.x >> 1, which = blockIdx.x & 1;
    const int tid = threadIdx.x, wave = tid>>6, lane = tid&63;
    __shared__ float xL[256];
    xL[tid] = x0g[b*256+tid] * (1.0f/256.0f);
    __syncthreads();
    const float* wmat = which ? icw : ihw;
    const float* bias = which ? icb : ihb;
    float* dst = which ? cx : hx0;
    const float4* x4 = (const float4*)xL;
    float4 xv = x4[lane];
    const float4* w4 = (const float4*)wmat;
    for (int r=wave; r<256; r+=4){
        float4 wv = w4[r*64+lane];
        float s = xv.x*wv.x + xv.y*wv.y + xv.z*wv.z + xv.w*wv.w;
#pragma unroll
        for (int off=32; off; off>>=1) s += __shfl_down(s,off,64);
        if (lane==0) dst[b*256+r] = tanhf(s + bias[r]);
    }
}

// ---------------- K7: one LSTM step ----------------
__global__ __launch_bounds__(128) void k_step(int t,
                                              const float* __restrict__ Gperm,
                                              const float* __restrict__ WpermT,
                                              const float* __restrict__ biasperm,
                                              const float* __restrict__ hxA,
                                              float* __restrict__ hxB,
                                              float* __restrict__ cx,
                                              const float* __restrict__ woutw,
                                              const float* __restrict__ woutb,
                                              float* __restrict__ preds){
    const int b = blockIdx.x >> 3, kc = blockIdx.x & 7;
    const int tid = threadIdx.x;
    __shared__ float hxL[256], gL[128];
    hxL[tid]     = hxA[b*256+tid];
    hxL[tid+128] = hxA[b*256+tid+128];
    __syncthreads();
    if (kc==0 && t>0){
        const int wave = tid>>6, lane=tid&63;
        const float4* w4 = (const float4*)(woutw + wave*256);
        const float4* h4 = (const float4*)hxL;
        float4 a = h4[lane], wv = w4[lane];
        float s = a.x*wv.x + a.y*wv.y + a.z*wv.z + a.w*wv.w;
#pragma unroll
        for (int off=32; off; off>>=1) s += __shfl_down(s,off,64);
        if (lane==0) preds[(t-1)*8 + b*2 + wave] = s + woutb[wave];
    }
    const int col = kc*128 + tid;
    float acc = Gperm[((size_t)(t*BB)+b)*1024 + col] + biasperm[col];
    const float* wp = WpermT + col;
#pragma unroll 8
    for (int d=0; d<256; ++d) acc = fmaf(hxL[d], wp[(size_t)d*1024], acc);
    gL[tid] = acc;
    __syncthreads();
    if (tid < 32){
        const int k = kc*32 + tid;
        float ig = gL[tid], fg = gL[32+tid], gg = gL[64+tid], og = gL[96+tid];
        float cn = sigm(fg)*cx[b*256+k] + sigm(ig)*tanhf(gg);
        float hn = sigm(og)*tanhf(cn);
        cx[b*256+k]  = cn;
        hxB[b*256+k] = hn;
    }
}

// ---------------- K8: final pred (t=99) ----------------
__global__ __launch_bounds__(128) void k_predfinal(const float* __restrict__ hx,
                                                   const float* __restrict__ woutw,
                                                   const float* __restrict__ woutb,
                                                   float* __restrict__ preds){
    const int b = blockIdx.x;
    const int tid = threadIdx.x, wave = tid>>6, lane = tid&63;
    __shared__ float hxL[256];
    hxL[tid] = hx[b*256+tid]; hxL[tid+128] = hx[b*256+tid+128];
    __syncthreads();
    const float4* w4 = (const float4*)(woutw + wave*256);
    const float4* h4 = (const float4*)hxL;
    float4 a = h4[lane], wv = w4[lane];
    float s = a.x*wv.x + a.y*wv.y + a.z*wv.z + a.w*wv.w;
#pragma unroll
    for (int off=32; off; off>>=1) s += __shfl_down(s,off,64);
    if (lane==0) preds[99*8 + b*2 + wave] = s + woutb[wave];
}

extern "C" void kernel_launch(void* const* d_in, const int* in_sizes, int n_in,
                              void* d_out, int out_size, void* d_ws, size_t ws_size,
                              hipStream_t stream){
    const float* cam   = (const float*)d_in[0];
    const float* convw = (const float*)d_in[1];
    const float* convb = (const float*)d_in[2];
    const float* gamma = (const float*)d_in[3];
    const float* beta  = (const float*)d_in[4];
    const float* ihw   = (const float*)d_in[5];
    const float* ihb   = (const float*)d_in[6];
    const float* icw   = (const float*)d_in[7];
    const float* icb   = (const float*)d_in[8];
    const float* ww    = (const float*)d_in[9];
    const float* wb    = (const float*)d_in[10];
    const float* wattn = (const float*)d_in[11];
    // d_in[12] = wattn_b: unused (softmax is shift-invariant)
    const float* wih   = (const float*)d_in[13];
    const float* whh   = (const float*)d_in[14];
    const float* bih   = (const float*)d_in[15];
    const float* bhh   = (const float*)d_in[16];
    const float* woutw = (const float*)d_in[17];
    const float* woutb = (const float*)d_in[18];
    float* out = (float*)d_out;

    char* wsb = (char*)d_ws;
    size_t off = 0;
    auto alloc = [&](size_t bytes)->void*{
        void* p = wsb + off; off += (bytes + 255) & ~(size_t)255; return p;
    };
    unsigned short* y   = (unsigned short*)alloc((size_t)NF*FRAME*2);
    unsigned short* wr2 = (unsigned short*)alloc((size_t)589824*2);
    float* scale    = (float*)alloc(256*4);
    float* shift    = (float*)alloc(256*4);
    float* x0g      = (float*)alloc(1024*4);
    float* ctx_f    = (float*)alloc((size_t)NF*256*4);
    float* Gperm    = (float*)alloc((size_t)NF*1024*4);
    float* WpermT   = (float*)alloc((size_t)262144*4);
    float* biasperm = (float*)alloc(1024*4);
    float* hx0      = (float*)alloc(1024*4);
    float* hx1      = (float*)alloc(1024*4);
    float* cx       = (float*)alloc(1024*4);

    hipLaunchKernelGGL(k_reorder2, dim3(2304), dim3(256), 0, stream, convw, wr2);
    hipLaunchKernelGGL(k_conv2, dim3(4, NF), dim3(256), 0, stream, cam, wr2, convb, y);
    hipLaunchKernelGGL(k_bnstats, dim3(256), dim3(256), 0, stream, y, gamma, beta, scale, shift);
    hipLaunchKernelGGL(k_frame, dim3(NF), dim3(256), 0, stream, y, scale, shift, wattn, out, ctx_f, x0g);
    hipLaunchKernelGGL(k_wcomb, dim3(1024), dim3(256), 0, stream, wih, whh, ww, wb, bih, bhh, WpermT, biasperm);
    hipLaunchKernelGGL(k_gperm, dim3(NF), dim3(256), 0, stream, ctx_f, wih, Gperm);
    hipLaunchKernelGGL(k_init, dim3(8), dim3(256), 0, stream, x0g, ihw, ihb, icw, icb, hx0, cx);
    for (int t=0; t<TT; ++t){
        float* hA = (t&1)? hx1 : hx0;
        float* hB = (t&1)? hx0 : hx1;
        hipLaunchKernelGGL(k_step, dim3(32), dim3(128), 0, stream, t,
                           Gperm, WpermT, biasperm, hA, hB, cx, woutw, woutb, out);
    }
    hipLaunchKernelGGL(k_predfinal, dim3(4), dim3(128), 0, stream, hx0, woutw, woutb, out);
}

// Round 3
// 962.835 us; speedup vs baseline: 5.5245x; 1.5568x over previous
//
#include <hip/hip_runtime.h>
#include <hip/hip_bf16.h>
#include <stdint.h>

#define BB 4
#define TT 100
#define DD 256
#define LL 256
#define NF (BB*TT)          // 400 frames
#define FRAME (DD*LL)       // 65536 elements per frame (ch * spatial)
#define EPSB 1e-5f

typedef __bf16  bf16x8 __attribute__((ext_vector_type(8)));
typedef float   f32x4  __attribute__((ext_vector_type(4)));

__device__ __forceinline__ float bf2f(unsigned short u){
    return __uint_as_float(((unsigned int)u) << 16);
}
__device__ __forceinline__ unsigned short f2bf(float f){
    __hip_bfloat16 h = __float2bfloat16(f);
    return *reinterpret_cast<unsigned short*>(&h);
}
__device__ __forceinline__ float sigm(float x){ return 1.0f/(1.0f+expf(-x)); }

// gate-col permutation: row r = g*256 + k  ->  col = (k>>6)*256 + g*64 + (k&63)
// so WG w of the scan owns hidden units k in [w*64,(w+1)*64) as local cols g*64+u.
__device__ __forceinline__ int permcol(int r){
    int g = r >> 8, k = r & 255;
    return ((k >> 6) << 8) + (g << 6) + (k & 63);
}

// ---------------- K0: reorder conv weights OIHW fp32 -> Wr2[tap][oc][ic] bf16 ----------------
__global__ void k_reorder2(const float* __restrict__ cw, unsigned short* __restrict__ wr){
    int idx = blockIdx.x*256 + threadIdx.x;          // 589824 total
    if (idx >= 256*256*9) return;
    int i  = idx & 255;
    int rest = idx >> 8;
    int o  = rest & 255;
    int t9 = rest >> 8;
    wr[idx] = f2bf(cw[((o<<8) + i)*9 + t9]);
}

// ---------------- K1: conv3x3 SAME + bias via MFMA implicit GEMM, bf16 y ----------------
#define XSTR 40
__global__ __launch_bounds__(256, 3) void k_conv2(const float* __restrict__ cam,
                                                  const unsigned short* __restrict__ wr,
                                                  const float* __restrict__ cb,
                                                  unsigned short* __restrict__ y){
    const int f   = blockIdx.y;
    const int oc0 = blockIdx.x * 64;
    const int tid = threadIdx.x;
    const int wv    = tid >> 6;
    const int quad  = (tid >> 4) & 3;
    const int wlane = tid & 15;

    __shared__ __align__(16) unsigned short Xl[324*XSTR];
    __shared__ __align__(16) unsigned short Al[192*XSTR];

    for (int i = tid; i < 324*XSTR/2; i += 256) ((unsigned int*)Xl)[i] = 0u;

    f32x4 acc[4][4];
#pragma unroll
    for (int mt=0; mt<4; ++mt){
        const int oc = oc0 + mt*16 + quad*4;
        f32x4 bv; bv[0]=cb[oc]; bv[1]=cb[oc+1]; bv[2]=cb[oc+2]; bv[3]=cb[oc+3];
#pragma unroll
        for (int nt=0; nt<4; ++nt) acc[mt][nt] = bv;
    }

    const int sp  = tid;
    const int spp = ((sp>>4)+1)*18 + (sp&15) + 1;
    const float* xs = cam + ((size_t)f*256)*256 + sp;

    for (int ck=0; ck<8; ++ck){
        const int c0 = ck*32;
        for (int tg=0; tg<3; ++tg){
            __syncthreads();
            if (tg == 0){
                const float* xc = xs + (size_t)c0*256;
#pragma unroll
                for (int jb=0; jb<4; ++jb){
                    unsigned int q0,q1,q2,q3;
                    {
                        float a0=xc[(jb*8+0)*256], a1=xc[(jb*8+1)*256];
                        float a2=xc[(jb*8+2)*256], a3=xc[(jb*8+3)*256];
                        float a4=xc[(jb*8+4)*256], a5=xc[(jb*8+5)*256];
                        float a6=xc[(jb*8+6)*256], a7=xc[(jb*8+7)*256];
                        q0 = (unsigned int)f2bf(a0) | ((unsigned int)f2bf(a1)<<16);
                        q1 = (unsigned int)f2bf(a2) | ((unsigned int)f2bf(a3)<<16);
                        q2 = (unsigned int)f2bf(a4) | ((unsigned int)f2bf(a5)<<16);
                        q3 = (unsigned int)f2bf(a6) | ((unsigned int)f2bf(a7)<<16);
                    }
                    uint4 qv; qv.x=q0; qv.y=q1; qv.z=q2; qv.w=q3;
                    *(uint4*)&Xl[spp*XSTR + jb*8] = qv;
                }
            }
            if (tid < 192){
                const unsigned short* src = wr +
                    ((size_t)((tg*3 + (tid>>6))*256 + oc0 + (tid&63)))*256 + c0;
                const uint4* s4 = (const uint4*)src;
                uint4* dq = (uint4*)(Al + tid*XSTR);
                dq[0]=s4[0]; dq[1]=s4[1]; dq[2]=s4[2]; dq[3]=s4[3];
            }
            __syncthreads();
#pragma unroll
            for (int cc=0; cc<3; ++cc){
                bf16x8 af[4], bfr[4];
#pragma unroll
                for (int mt=0; mt<4; ++mt)
                    af[mt] = *(const bf16x8*)(Al + ((cc*64 + mt*16 + wlane)*XSTR + quad*8));
#pragma unroll
                for (int nt=0; nt<4; ++nt){
                    const int hh = wv*4 + nt;
                    const int pp = (hh + tg)*18 + wlane + cc;
                    bfr[nt] = *(const bf16x8*)(Xl + (pp*XSTR + quad*8));
                }
#pragma unroll
                for (int mt=0; mt<4; ++mt)
#pragma unroll
                    for (int nt=0; nt<4; ++nt)
                        acc[mt][nt] = __builtin_amdgcn_mfma_f32_16x16x32_bf16(
                            af[mt], bfr[nt], acc[mt][nt], 0, 0, 0);
            }
        }
    }

#pragma unroll
    for (int mt=0; mt<4; ++mt){
        const int oc = oc0 + mt*16 + quad*4;
#pragma unroll
        for (int nt=0; nt<4; ++nt){
            const int p = (wv*4 + nt)*16 + wlane;
#pragma unroll
            for (int reg=0; reg<4; ++reg)
                y[((size_t)(f*256) + oc + reg)*256 + p] = f2bf(acc[mt][nt][reg]);
        }
    }
}

// ---------------- K2: BN batch stats -> scale/shift per channel ----------------
__global__ __launch_bounds__(256) void k_bnstats(const unsigned short* __restrict__ y,
                                                 const float* __restrict__ gamma,
                                                 const float* __restrict__ beta,
                                                 float* __restrict__ scale,
                                                 float* __restrict__ shift){
    const int c = blockIdx.x, tid = threadIdx.x;
    float s=0.f, q=0.f;
    for (int f=0; f<NF; ++f){
        float v = bf2f(y[(size_t)f*FRAME + c*256 + tid]);
        s += v; q += v*v;
    }
    __shared__ float rs[4], rq[4];
    int lane = tid&63, wave = tid>>6;
#pragma unroll
    for (int off=32; off; off>>=1){ s += __shfl_down(s,off,64); q += __shfl_down(q,off,64); }
    if (lane==0){ rs[wave]=s; rq[wave]=q; }
    __syncthreads();
    if (tid==0){
        s = rs[0]+rs[1]+rs[2]+rs[3];
        q = rq[0]+rq[1]+rq[2]+rq[3];
        const float invN = 1.0f/(float)(NF*256);
        float mean = s*invN;
        float var  = q*invN - mean*mean;
        float istd = rsqrtf(var + EPSB);
        float sc = gamma[c]*istd;
        scale[c] = sc;
        shift[c] = beta[c] - mean*sc;
    }
}

// ---------------- K3: per-frame fdot -> softmax -> alpha/logp out, ctx_f, x0 ----------------
__global__ __launch_bounds__(256) void k_frame(const unsigned short* __restrict__ y,
                                               const float* __restrict__ scale,
                                               const float* __restrict__ shift,
                                               const float* __restrict__ wattn,
                                               float* __restrict__ d_out,
                                               float* __restrict__ ctx_f,
                                               float* __restrict__ x0g){
    const int f = blockIdx.x, tid = threadIdx.x;
    const int b = f / TT, t = f - b*TT;
    const int wave = tid>>6, lane = tid&63;
    __shared__ float fdotL[256], alphaL[256], x0acc[256], wattnL[256];
    __shared__ float redM[4], redS[4];
    wattnL[tid] = wattn[tid];
    x0acc[tid] = 0.f;
    __syncthreads();
    const bool isT0 = (t==0);
    const float wl0 = wattnL[lane*4+0], wl1 = wattnL[lane*4+1];
    const float wl2 = wattnL[lane*4+2], wl3 = wattnL[lane*4+3];
    const ushort4* y4 = (const ushort4*)(y + (size_t)f*FRAME);
    for (int ci=0; ci<64; ++ci){
        int c = wave + ci*4;
        ushort4 u = y4[c*64 + lane];
        float sc = scale[c], sh = shift[c];
        float v0 = fmaxf(fmaf(bf2f(u.x),sc,sh),0.f);
        float v1 = fmaxf(fmaf(bf2f(u.y),sc,sh),0.f);
        float v2 = fmaxf(fmaf(bf2f(u.z),sc,sh),0.f);
        float v3 = fmaxf(fmaf(bf2f(u.w),sc,sh),0.f);
        float s = v0*wl0 + v1*wl1 + v2*wl2 + v3*wl3;
#pragma unroll
        for (int off=32; off; off>>=1) s += __shfl_down(s,off,64);
        if (lane==0) fdotL[c] = s;
        if (isT0){
            atomicAdd(&x0acc[lane*4+0], v0);
            atomicAdd(&x0acc[lane*4+1], v1);
            atomicAdd(&x0acc[lane*4+2], v2);
            atomicAdd(&x0acc[lane*4+3], v3);
        }
    }
    __syncthreads();
    float v = fdotL[tid];
    float m = v;
#pragma unroll
    for (int off=32; off; off>>=1) m = fmaxf(m, __shfl_down(m,off,64));
    if (lane==0) redM[wave]=m;
    __syncthreads();
    m = fmaxf(fmaxf(redM[0],redM[1]),fmaxf(redM[2],redM[3]));
    float e = expf(v-m);
    float ss = e;
#pragma unroll
    for (int off=32; off; off>>=1) ss += __shfl_down(ss,off,64);
    if (lane==0) redS[wave]=ss;
    __syncthreads();
    float S = redS[0]+redS[1]+redS[2]+redS[3];
    float logS = logf(S);
    float alpha = e / S;
    d_out[800    + ((t*BB)+b)*256 + tid] = alpha;
    d_out[103200 + ((t*BB)+b)*256 + tid] = v - m - logS;
    alphaL[tid] = alpha;
    if (isT0) x0g[b*256+tid] = x0acc[tid];
    __syncthreads();
    const unsigned short* yf = y + (size_t)f*FRAME;
    float ctx = 0.f;
    for (int c=0;c<256;++c){
        float yv = fmaxf(fmaf(bf2f(yf[c*256+tid]), scale[c], shift[c]), 0.f);
        ctx = fmaf(yv, alphaL[c], ctx);
    }
    ctx_f[f*256+tid] = ctx;
}

// ---------------- K4: Gperm[t,b,col] = ctx_f[f] . wih[r], gate-permuted ----------------
__global__ __launch_bounds__(256) void k_gperm(const float* __restrict__ ctx_f,
                                               const float* __restrict__ wih,
                                               float* __restrict__ Gperm){
    const int f = blockIdx.x, tid = threadIdx.x;
    const int b = f / TT, t = f - b*TT;
    __shared__ float ctxL[256];
    ctxL[tid] = ctx_f[f*256+tid];
    __syncthreads();
    const int wave = tid>>6, lane = tid&63;
    const float4* c4 = (const float4*)ctxL;
    float4 cv = c4[lane];
    const float4* w4 = (const float4*)wih;
    float* gout = Gperm + ((size_t)(t*BB)+b)*1024;
    for (int r=wave; r<1024; r+=4){
        float4 wv = w4[r*64 + lane];
        float s = cv.x*wv.x + cv.y*wv.y + cv.z*wv.z + cv.w*wv.w;
#pragma unroll
        for (int off=32; off; off>>=1) s += __shfl_down(s,off,64);
        if (lane==0) gout[permcol(r)] = s;
    }
}

// ---------------- K5: W_comb = whh + wih@w_w -> WbfT[col][d] bf16 (transposed, permuted) ----------------
__global__ __launch_bounds__(256) void k_wcomb(const float* __restrict__ wih,
                                               const float* __restrict__ whh,
                                               const float* __restrict__ ww,
                                               const float* __restrict__ wb,
                                               const float* __restrict__ bih,
                                               const float* __restrict__ bhh,
                                               unsigned short* __restrict__ WbfT,
                                               float* __restrict__ biasperm){
    const int r = blockIdx.x, tid = threadIdx.x;
    __shared__ float wihL[256];
    wihL[tid] = wih[r*256+tid];
    __syncthreads();
    float acc = whh[r*256+tid];
    for (int k=0;k<256;++k) acc = fmaf(wihL[k], ww[k*256+tid], acc);
    const int col = permcol(r);
    WbfT[(size_t)col*256 + tid] = f2bf(acc);
    if (tid < 64){
        float s = 0.f;
#pragma unroll
        for (int q=0;q<4;++q) s += wihL[tid + 64*q] * wb[tid + 64*q];
#pragma unroll
        for (int off=32; off; off>>=1) s += __shfl_down(s,off,64);
        if (tid==0) biasperm[col] = bih[r] + bhh[r] + s;
    }
}

// ---------------- K6: initial hx/cx = tanh(x0 @ W.T + b); hx -> hxg buf0 ----------------
__global__ __launch_bounds__(256) void k_init(const float* __restrict__ x0g,
                                              const float* __restrict__ ihw,
                                              const float* __restrict__ ihb,
                                              const float* __restrict__ icw,
                                              const float* __restrict__ icb,
                                              float* __restrict__ hxg,
                                              float* __restrict__ cxg){
    const int b = blockIdx.x >> 1, which = blockIdx.x & 1;
    const int tid = threadIdx.x, wave = tid>>6, lane = tid&63;
    __shared__ float xL[256];
    xL[tid] = x0g[b*256+tid] * (1.0f/256.0f);
    __syncthreads();
    const float* wmat = which ? icw : ihw;
    const float* bias = which ? icb : ihb;
    float* dst = which ? cxg : hxg;    // hxg = buffer 0
    const float4* x4 = (const float4*)xL;
    float4 xv = x4[lane];
    const float4* w4 = (const float4*)wmat;
    for (int r=wave; r<256; r+=4){
        float4 wv = w4[r*64+lane];
        float s = xv.x*wv.x + xv.y*wv.y + xv.z*wv.z + xv.w*wv.w;
#pragma unroll
        for (int off=32; off; off>>=1) s += __shfl_down(s,off,64);
        if (lane==0) dst[b*256+r] = tanhf(s + bias[r]);
    }
}

// ---------------- K7: zero barrier counters, init preds with output bias ----------------
__global__ void k_zero(float* __restrict__ out, const float* __restrict__ woutb,
                       unsigned int* __restrict__ bar){
    int i = blockIdx.x*256 + threadIdx.x;
    if (i < 800) out[i] = woutb[i & 1];
    if (i < 128) bar[i] = 0u;
}

// ---------------- K8: persistent LSTM scan ----------------
// 4 WGs x 256 threads. WG w owns hidden units k in [w*64,(w+1)*64) (=256 gate cols).
// Weights register-resident as MFMA B-frags; hx exchanged via double-buffered global
// with agent-scope atomics + per-step monotonic barrier counters.
#define HSTR 280   // hxL row stride in ushorts: 560B, 16B-aligned, 2-way banks (free)
__global__ __launch_bounds__(256, 1) void k_scan(const unsigned short* __restrict__ WbfT,
                                                 const float* __restrict__ biasperm,
                                                 const float* __restrict__ Gperm,
                                                 const float* __restrict__ cxg,
                                                 float* __restrict__ hxg,   // [2][1024]
                                                 const float* __restrict__ woutw,
                                                 float* __restrict__ out,
                                                 unsigned int* __restrict__ bar){
    const int w   = blockIdx.x;          // 0..3
    const int tid = threadIdx.x;
    const int wv  = tid >> 6, lane = tid & 63;
    const int m16 = lane & 15, quad = lane >> 4;

    __shared__ __align__(16) unsigned short hxL[16*HSTR];
    __shared__ __align__(16) float gl[256*4];
    __shared__ float biasL[256];

    for (int i = tid; i < 16*HSTR/2; i += 256) ((unsigned int*)hxL)[i] = 0u;
    biasL[tid] = biasperm[w*256 + tid];

    // register-resident weight B-fragments: wave wv owns local col tiles wv*4..wv*4+3
    bf16x8 bfrag[4][8];
#pragma unroll
    for (int ct=0; ct<4; ++ct){
        const int col = w*256 + (wv*4 + ct)*16 + m16;
        const unsigned short* cp = WbfT + (size_t)col*256;
#pragma unroll
        for (int kt=0; kt<8; ++kt)
            bfrag[ct][kt] = *(const bf16x8*)(cp + kt*32 + quad*8);
    }

    // elementwise thread identity: wave = batch, lane = unit
    const int eb = wv, eu = lane, ek = w*64 + eu;
    float cxr = cxg[eb*256 + ek];
    const float w0 = woutw[ek], w1 = woutw[256 + ek];
    __syncthreads();

    for (int t=0; t<TT; ++t){
        // stage hx(t) -> LDS bf16 (rows 0-3; rows 4-15 stay zero)
        {
            const float* hsrc = hxg + (t & 1)*1024;
            const int j0 = tid*4;
#pragma unroll
            for (int q=0; q<4; ++q){
                unsigned int uv = __hip_atomic_load((const unsigned int*)hsrc + j0 + q,
                                                    __ATOMIC_RELAXED, __HIP_MEMORY_SCOPE_AGENT);
                hxL[((j0+q)>>8)*HSTR + ((j0+q)&255)] = f2bf(__uint_as_float(uv));
            }
        }
        // prefetch Gperm slice for elementwise phase
        float gp[4];
        {
            const float* gsrc = Gperm + ((size_t)t*4 + eb)*1024 + w*256 + eu;
#pragma unroll
            for (int g=0; g<4; ++g) gp[g] = gsrc[g*64];
        }
        __syncthreads();

        // A-frags from LDS, MFMA
        bf16x8 afr[8];
#pragma unroll
        for (int kt=0; kt<8; ++kt)
            afr[kt] = *(const bf16x8*)(hxL + m16*HSTR + kt*32 + quad*8);
        f32x4 acc[4];
#pragma unroll
        for (int ct=0; ct<4; ++ct){ acc[ct][0]=0.f; acc[ct][1]=0.f; acc[ct][2]=0.f; acc[ct][3]=0.f; }
#pragma unroll
        for (int ct=0; ct<4; ++ct)
#pragma unroll
            for (int kt=0; kt<8; ++kt)
                acc[ct] = __builtin_amdgcn_mfma_f32_16x16x32_bf16(afr[kt], bfrag[ct][kt], acc[ct], 0,0,0);

        // D rows 0-3 (batches) live in lanes 0-15, regs 0-3
        if (lane < 16){
#pragma unroll
            for (int ct=0; ct<4; ++ct){
                const int c = (wv*4 + ct)*16 + lane;
                float4 v; v.x=acc[ct][0]; v.y=acc[ct][1]; v.z=acc[ct][2]; v.w=acc[ct][3];
                *(float4*)&gl[c*4] = v;
            }
        }
        __syncthreads();

        // elementwise LSTM update (thread = (batch eb, unit eu))
        float gi = gl[(      eu)*4 + eb] + gp[0] + biasL[      eu];
        float gf = gl[( 64 + eu)*4 + eb] + gp[1] + biasL[ 64 + eu];
        float gg = gl[(128 + eu)*4 + eb] + gp[2] + biasL[128 + eu];
        float go = gl[(192 + eu)*4 + eb] + gp[3] + biasL[192 + eu];
        float cn = sigm(gf)*cxr + sigm(gi)*tanhf(gg);
        float hn = sigm(go)*tanhf(cn);
        cxr = cn;

        // preds partial: reduce over 64 units in this wave
        float p0 = hn*w0, p1 = hn*w1;
#pragma unroll
        for (int off=32; off; off>>=1){ p0 += __shfl_down(p0,off,64); p1 += __shfl_down(p1,off,64); }
        if (eu == 0){
            atomicAdd(&out[t*8 + eb*2 + 0], p0);
            atomicAdd(&out[t*8 + eb*2 + 1], p1);
        }

        if (t < TT-1){
            // publish hx slice (device-visible), barrier, acquire
            __hip_atomic_store((unsigned int*)(hxg + ((t+1)&1)*1024 + eb*256 + ek),
                               __float_as_uint(hn), __ATOMIC_RELAXED, __HIP_MEMORY_SCOPE_AGENT);
            __syncthreads();   // all stores issued (vmcnt drained at barrier)
            if (tid == 0){
                __hip_atomic_fetch_add(bar + t, 1u, __ATOMIC_RELEASE, __HIP_MEMORY_SCOPE_AGENT);
                while (__hip_atomic_load(bar + t, __ATOMIC_ACQUIRE, __HIP_MEMORY_SCOPE_AGENT) < 4u)
                    __builtin_amdgcn_s_sleep(1);
            }
            __syncthreads();
            __builtin_amdgcn_fence(__ATOMIC_ACQUIRE, "agent");
        }
    }
}

extern "C" void kernel_launch(void* const* d_in, const int* in_sizes, int n_in,
                              void* d_out, int out_size, void* d_ws, size_t ws_size,
                              hipStream_t stream){
    const float* cam   = (const float*)d_in[0];
    const float* convw = (const float*)d_in[1];
    const float* convb = (const float*)d_in[2];
    const float* gamma = (const float*)d_in[3];
    const float* beta  = (const float*)d_in[4];
    const float* ihw   = (const float*)d_in[5];
    const float* ihb   = (const float*)d_in[6];
    const float* icw   = (const float*)d_in[7];
    const float* icb   = (const float*)d_in[8];
    const float* ww    = (const float*)d_in[9];
    const float* wb    = (const float*)d_in[10];
    const float* wattn = (const float*)d_in[11];
    // d_in[12] = wattn_b: unused (softmax is shift-invariant)
    const float* wih   = (const float*)d_in[13];
    const float* whh   = (const float*)d_in[14];
    const float* bih   = (const float*)d_in[15];
    const float* bhh   = (const float*)d_in[16];
    const float* woutw = (const float*)d_in[17];
    const float* woutb = (const float*)d_in[18];
    float* out = (float*)d_out;

    char* wsb = (char*)d_ws;
    size_t off = 0;
    auto alloc = [&](size_t bytes)->void*{
        void* p = wsb + off; off += (bytes + 255) & ~(size_t)255; return p;
    };
    unsigned short* y    = (unsigned short*)alloc((size_t)NF*FRAME*2);
    unsigned short* wr2  = (unsigned short*)alloc((size_t)589824*2);
    unsigned short* WbfT = (unsigned short*)alloc((size_t)262144*2);
    float* scale    = (float*)alloc(256*4);
    float* shift    = (float*)alloc(256*4);
    float* x0g      = (float*)alloc(1024*4);
    float* ctx_f    = (float*)alloc((size_t)NF*256*4);
    float* Gperm    = (float*)alloc((size_t)NF*1024*4);
    float* biasperm = (float*)alloc(1024*4);
    float* hxg      = (float*)alloc(2048*4);
    float* cxg      = (float*)alloc(1024*4);
    unsigned int* bar = (unsigned int*)alloc(128*4);

    hipLaunchKernelGGL(k_zero, dim3(4), dim3(256), 0, stream, out, woutb, bar);
    hipLaunchKernelGGL(k_reorder2, dim3(2304), dim3(256), 0, stream, convw, wr2);
    hipLaunchKernelGGL(k_conv2, dim3(4, NF), dim3(256), 0, stream, cam, wr2, convb, y);
    hipLaunchKernelGGL(k_bnstats, dim3(256), dim3(256), 0, stream, y, gamma, beta, scale, shift);
    hipLaunchKernelGGL(k_frame, dim3(NF), dim3(256), 0, stream, y, scale, shift, wattn, out, ctx_f, x0g);
    hipLaunchKernelGGL(k_wcomb, dim3(1024), dim3(256), 0, stream, wih, whh, ww, wb, bih, bhh, WbfT, biasperm);
    hipLaunchKernelGGL(k_gperm, dim3(NF), dim3(256), 0, stream, ctx_f, wih, Gperm);
    hipLaunchKernelGGL(k_init, dim3(8), dim3(256), 0, stream, x0g, ihw, ihb, icw, icb, hxg, cxg);
    hipLaunchKernelGGL(k_scan, dim3(4), dim3(256), 0, stream,
                       WbfT, biasperm, Gperm, cxg, hxg, woutw, out, bar);
}

// Round 4
// 810.860 us; speedup vs baseline: 6.5599x; 1.1874x over previous
//
#include <hip/hip_runtime.h>
#include <hip/hip_bf16.h>
#include <stdint.h>

#define BB 4
#define TT 100
#define DD 256
#define LL 256
#define NF (BB*TT)          // 400 frames
#define FRAME (DD*LL)       // 65536 elements per frame (ch * spatial)
#define EPSB 1e-5f

typedef __bf16  bf16x8 __attribute__((ext_vector_type(8)));
typedef float   f32x4  __attribute__((ext_vector_type(4)));
typedef int     i32x4  __attribute__((ext_vector_type(4)));

__device__ __forceinline__ float bf2f(unsigned short u){
    return __uint_as_float(((unsigned int)u) << 16);
}
__device__ __forceinline__ unsigned short f2bf(float f){
    __hip_bfloat16 h = __float2bfloat16(f);
    return *reinterpret_cast<unsigned short*>(&h);
}
__device__ __forceinline__ float sigm(float x){ return 1.0f/(1.0f+expf(-x)); }
__device__ __forceinline__ int8_t q8(float x){
    int v = (int)lrintf(x);
    v = v < -127 ? -127 : (v > 127 ? 127 : v);
    return (int8_t)v;
}

// W_comb col slot mapping for the single-WG scan:
// gate row r = g*256 + u ; u = wv*32 + e*16 + n (wv=wave 0..7, e=0/1, n=0..15)
// wave-local col tile ct = g*2 + e. B-frag k slot: k = kt*64 + quad*16 + j.
// Packed byte offset (consistent A/B k-mapping makes exact HW k-order irrelevant):
__device__ __forceinline__ size_t wq_off(int r, int k){
    int g = r >> 8, u = r & 255;
    int wv = u >> 5, e = (u >> 4) & 1, n = u & 15;
    int ct = g*2 + e;
    int kt = k >> 6, quad = (k >> 4) & 3, j = k & 15;
    return ((size_t)(((wv*8 + ct)*4 + kt)*4 + quad)*16 + n)*16 + j;
}

// ---------------- K0: reorder conv weights OIHW fp32 -> Wr2[tap][oc][ic] bf16 ----------------
__global__ void k_reorder2(const float* __restrict__ cw, unsigned short* __restrict__ wr){
    int idx = blockIdx.x*256 + threadIdx.x;          // 589824 total
    if (idx >= 256*256*9) return;
    int i  = idx & 255;
    int rest = idx >> 8;
    int o  = rest & 255;
    int t9 = rest >> 8;
    wr[idx] = f2bf(cw[((o<<8) + i)*9 + t9]);
}

// ---------------- K1: conv3x3 SAME + bias via MFMA implicit GEMM, bf16 y ----------------
#define XSTR 40
__global__ __launch_bounds__(256, 3) void k_conv2(const float* __restrict__ cam,
                                                  const unsigned short* __restrict__ wr,
                                                  const float* __restrict__ cb,
                                                  unsigned short* __restrict__ y){
    const int f   = blockIdx.y;
    const int oc0 = blockIdx.x * 64;
    const int tid = threadIdx.x;
    const int wv    = tid >> 6;
    const int quad  = (tid >> 4) & 3;
    const int wlane = tid & 15;

    __shared__ __align__(16) unsigned short Xl[324*XSTR];
    __shared__ __align__(16) unsigned short Al[192*XSTR];

    for (int i = tid; i < 324*XSTR/2; i += 256) ((unsigned int*)Xl)[i] = 0u;

    f32x4 acc[4][4];
#pragma unroll
    for (int mt=0; mt<4; ++mt){
        const int oc = oc0 + mt*16 + quad*4;
        f32x4 bv; bv[0]=cb[oc]; bv[1]=cb[oc+1]; bv[2]=cb[oc+2]; bv[3]=cb[oc+3];
#pragma unroll
        for (int nt=0; nt<4; ++nt) acc[mt][nt] = bv;
    }

    const int sp  = tid;
    const int spp = ((sp>>4)+1)*18 + (sp&15) + 1;
    const float* xs = cam + ((size_t)f*256)*256 + sp;

    for (int ck=0; ck<8; ++ck){
        const int c0 = ck*32;
        for (int tg=0; tg<3; ++tg){
            __syncthreads();
            if (tg == 0){
                const float* xc = xs + (size_t)c0*256;
#pragma unroll
                for (int jb=0; jb<4; ++jb){
                    unsigned int q0,q1,q2,q3;
                    {
                        float a0=xc[(jb*8+0)*256], a1=xc[(jb*8+1)*256];
                        float a2=xc[(jb*8+2)*256], a3=xc[(jb*8+3)*256];
                        float a4=xc[(jb*8+4)*256], a5=xc[(jb*8+5)*256];
                        float a6=xc[(jb*8+6)*256], a7=xc[(jb*8+7)*256];
                        q0 = (unsigned int)f2bf(a0) | ((unsigned int)f2bf(a1)<<16);
                        q1 = (unsigned int)f2bf(a2) | ((unsigned int)f2bf(a3)<<16);
                        q2 = (unsigned int)f2bf(a4) | ((unsigned int)f2bf(a5)<<16);
                        q3 = (unsigned int)f2bf(a6) | ((unsigned int)f2bf(a7)<<16);
                    }
                    uint4 qv; qv.x=q0; qv.y=q1; qv.z=q2; qv.w=q3;
                    *(uint4*)&Xl[spp*XSTR + jb*8] = qv;
                }
            }
            if (tid < 192){
                const unsigned short* src = wr +
                    ((size_t)((tg*3 + (tid>>6))*256 + oc0 + (tid&63)))*256 + c0;
                const uint4* s4 = (const uint4*)src;
                uint4* dq = (uint4*)(Al + tid*XSTR);
                dq[0]=s4[0]; dq[1]=s4[1]; dq[2]=s4[2]; dq[3]=s4[3];
            }
            __syncthreads();
#pragma unroll
            for (int cc=0; cc<3; ++cc){
                bf16x8 af[4], bfr[4];
#pragma unroll
                for (int mt=0; mt<4; ++mt)
                    af[mt] = *(const bf16x8*)(Al + ((cc*64 + mt*16 + wlane)*XSTR + quad*8));
#pragma unroll
                for (int nt=0; nt<4; ++nt){
                    const int hh = wv*4 + nt;
                    const int pp = (hh + tg)*18 + wlane + cc;
                    bfr[nt] = *(const bf16x8*)(Xl + (pp*XSTR + quad*8));
                }
#pragma unroll
                for (int mt=0; mt<4; ++mt)
#pragma unroll
                    for (int nt=0; nt<4; ++nt)
                        acc[mt][nt] = __builtin_amdgcn_mfma_f32_16x16x32_bf16(
                            af[mt], bfr[nt], acc[mt][nt], 0, 0, 0);
            }
        }
    }

#pragma unroll
    for (int mt=0; mt<4; ++mt){
        const int oc = oc0 + mt*16 + quad*4;
#pragma unroll
        for (int nt=0; nt<4; ++nt){
            const int p = (wv*4 + nt)*16 + wlane;
#pragma unroll
            for (int reg=0; reg<4; ++reg)
                y[((size_t)(f*256) + oc + reg)*256 + p] = f2bf(acc[mt][nt][reg]);
        }
    }
}

// ---------------- K2: BN batch stats -> scale/shift per channel ----------------
__global__ __launch_bounds__(256) void k_bnstats(const unsigned short* __restrict__ y,
                                                 const float* __restrict__ gamma,
                                                 const float* __restrict__ beta,
                                                 float* __restrict__ scale,
                                                 float* __restrict__ shift){
    const int c = blockIdx.x, tid = threadIdx.x;
    float s=0.f, q=0.f;
    for (int f=0; f<NF; ++f){
        float v = bf2f(y[(size_t)f*FRAME + c*256 + tid]);
        s += v; q += v*v;
    }
    __shared__ float rs[4], rq[4];
    int lane = tid&63, wave = tid>>6;
#pragma unroll
    for (int off=32; off; off>>=1){ s += __shfl_down(s,off,64); q += __shfl_down(q,off,64); }
    if (lane==0){ rs[wave]=s; rq[wave]=q; }
    __syncthreads();
    if (tid==0){
        s = rs[0]+rs[1]+rs[2]+rs[3];
        q = rq[0]+rq[1]+rq[2]+rq[3];
        const float invN = 1.0f/(float)(NF*256);
        float mean = s*invN;
        float var  = q*invN - mean*mean;
        float istd = rsqrtf(var + EPSB);
        float sc = gamma[c]*istd;
        scale[c] = sc;
        shift[c] = beta[c] - mean*sc;
    }
}

// ---------------- K3: per-frame fdot -> softmax -> alpha/logp out, ctx_f, x0 ----------------
__global__ __launch_bounds__(256) void k_frame(const unsigned short* __restrict__ y,
                                               const float* __restrict__ scale,
                                               const float* __restrict__ shift,
                                               const float* __restrict__ wattn,
                                               float* __restrict__ d_out,
                                               float* __restrict__ ctx_f,
                                               float* __restrict__ x0g){
    const int f = blockIdx.x, tid = threadIdx.x;
    const int b = f / TT, t = f - b*TT;
    const int wave = tid>>6, lane = tid&63;
    __shared__ float fdotL[256], alphaL[256], x0acc[256], wattnL[256];
    __shared__ float redM[4], redS[4];
    wattnL[tid] = wattn[tid];
    x0acc[tid] = 0.f;
    __syncthreads();
    const bool isT0 = (t==0);
    const float wl0 = wattnL[lane*4+0], wl1 = wattnL[lane*4+1];
    const float wl2 = wattnL[lane*4+2], wl3 = wattnL[lane*4+3];
    const ushort4* y4 = (const ushort4*)(y + (size_t)f*FRAME);
    for (int ci=0; ci<64; ++ci){
        int c = wave + ci*4;
        ushort4 u = y4[c*64 + lane];
        float sc = scale[c], sh = shift[c];
        float v0 = fmaxf(fmaf(bf2f(u.x),sc,sh),0.f);
        float v1 = fmaxf(fmaf(bf2f(u.y),sc,sh),0.f);
        float v2 = fmaxf(fmaf(bf2f(u.z),sc,sh),0.f);
        float v3 = fmaxf(fmaf(bf2f(u.w),sc,sh),0.f);
        float s = v0*wl0 + v1*wl1 + v2*wl2 + v3*wl3;
#pragma unroll
        for (int off=32; off; off>>=1) s += __shfl_down(s,off,64);
        if (lane==0) fdotL[c] = s;
        if (isT0){
            atomicAdd(&x0acc[lane*4+0], v0);
            atomicAdd(&x0acc[lane*4+1], v1);
            atomicAdd(&x0acc[lane*4+2], v2);
            atomicAdd(&x0acc[lane*4+3], v3);
        }
    }
    __syncthreads();
    float v = fdotL[tid];
    float m = v;
#pragma unroll
    for (int off=32; off; off>>=1) m = fmaxf(m, __shfl_down(m,off,64));
    if (lane==0) redM[wave]=m;
    __syncthreads();
    m = fmaxf(fmaxf(redM[0],redM[1]),fmaxf(redM[2],redM[3]));
    float e = expf(v-m);
    float ss = e;
#pragma unroll
    for (int off=32; off; off>>=1) ss += __shfl_down(ss,off,64);
    if (lane==0) redS[wave]=ss;
    __syncthreads();
    float S = redS[0]+redS[1]+redS[2]+redS[3];
    float logS = logf(S);
    float alpha = e / S;
    d_out[800    + ((t*BB)+b)*256 + tid] = alpha;
    d_out[103200 + ((t*BB)+b)*256 + tid] = v - m - logS;
    alphaL[tid] = alpha;
    if (isT0) x0g[b*256+tid] = x0acc[tid];
    __syncthreads();
    const unsigned short* yf = y + (size_t)f*FRAME;
    float ctx = 0.f;
    for (int c=0;c<256;++c){
        float yv = fmaxf(fmaf(bf2f(yf[c*256+tid]), scale[c], shift[c]), 0.f);
        ctx = fmaf(yv, alphaL[c], ctx);
    }
    ctx_f[f*256+tid] = ctx;
}

// ---------------- K4: Gperm[t,b,r] = ctx_f[f] . wih[r]  (natural order) ----------------
__global__ __launch_bounds__(256) void k_gperm(const float* __restrict__ ctx_f,
                                               const float* __restrict__ wih,
                                               float* __restrict__ Gperm){
    const int f = blockIdx.x, tid = threadIdx.x;
    const int b = f / TT, t = f - b*TT;
    __shared__ float ctxL[256];
    ctxL[tid] = ctx_f[f*256+tid];
    __syncthreads();
    const int wave = tid>>6, lane = tid&63;
    const float4* c4 = (const float4*)ctxL;
    float4 cv = c4[lane];
    const float4* w4 = (const float4*)wih;
    float* gout = Gperm + ((size_t)(t*BB)+b)*1024;
    for (int r=wave; r<1024; r+=4){
        float4 wv = w4[r*64 + lane];
        float s = cv.x*wv.x + cv.y*wv.y + cv.z*wv.z + cv.w*wv.w;
#pragma unroll
        for (int off=32; off; off>>=1) s += __shfl_down(s,off,64);
        if (lane==0) gout[r] = s;
    }
}

// ---------------- K5: W_comb = whh + wih@w_w -> int8 frag-packed + per-row dq scale ----------------
__global__ __launch_bounds__(256) void k_wcomb(const float* __restrict__ wih,
                                               const float* __restrict__ whh,
                                               const float* __restrict__ ww,
                                               const float* __restrict__ wb,
                                               const float* __restrict__ bih,
                                               const float* __restrict__ bhh,
                                               int8_t* __restrict__ Wq,
                                               float* __restrict__ dqs,
                                               float* __restrict__ biasg){
    const int r = blockIdx.x, tid = threadIdx.x;
    const int lane = tid&63, wave = tid>>6;
    __shared__ float wihL[256];
    __shared__ float red[4];
    __shared__ float smaxs;
    wihL[tid] = wih[r*256+tid];
    __syncthreads();
    float acc = whh[r*256+tid];
    for (int k=0;k<256;++k) acc = fmaf(wihL[k], ww[k*256+tid], acc);
    // row max(|acc|)
    float m = fabsf(acc);
#pragma unroll
    for (int off=32; off; off>>=1) m = fmaxf(m, __shfl_down(m,off,64));
    if (lane==0) red[wave] = m;
    __syncthreads();
    if (tid==0){
        float s = fmaxf(fmaxf(red[0],red[1]),fmaxf(red[2],red[3]));
        smaxs = (s > 1e-30f) ? s : 1.0f;
        dqs[r] = smaxs * (1.0f/16129.0f);   // smax/(127*127)
    }
    __syncthreads();
    float inv = 127.0f / smaxs;
    Wq[wq_off(r, tid)] = q8(acc * inv);
    if (tid < 64){
        float s = 0.f;
#pragma unroll
        for (int q=0;q<4;++q) s += wihL[tid + 64*q] * wb[tid + 64*q];
#pragma unroll
        for (int off=32; off; off>>=1) s += __shfl_down(s,off,64);
        if (tid==0) biasg[r] = bih[r] + bhh[r] + s;
    }
}

// ---------------- K6: initial hx/cx = tanh(x0 @ W.T + b) ----------------
__global__ __launch_bounds__(256) void k_init(const float* __restrict__ x0g,
                                              const float* __restrict__ ihw,
                                              const float* __restrict__ ihb,
                                              const float* __restrict__ icw,
                                              const float* __restrict__ icb,
                                              float* __restrict__ hxg,
                                              float* __restrict__ cxg){
    const int b = blockIdx.x >> 1, which = blockIdx.x & 1;
    const int tid = threadIdx.x, wave = tid>>6, lane = tid&63;
    __shared__ float xL[256];
    xL[tid] = x0g[b*256+tid] * (1.0f/256.0f);
    __syncthreads();
    const float* wmat = which ? icw : ihw;
    const float* bias = which ? icb : ihb;
    float* dst = which ? cxg : hxg;
    const float4* x4 = (const float4*)xL;
    float4 xv = x4[lane];
    const float4* w4 = (const float4*)wmat;
    for (int r=wave; r<256; r+=4){
        float4 wv = w4[r*64+lane];
        float s = xv.x*wv.x + xv.y*wv.y + xv.z*wv.z + xv.w*wv.w;
#pragma unroll
        for (int off=32; off; off>>=1) s += __shfl_down(s,off,64);
        if (lane==0) dst[b*256+r] = tanhf(s + bias[r]);
    }
}

// ---------------- K7: init preds with output bias ----------------
__global__ void k_zero(float* __restrict__ out, const float* __restrict__ woutb){
    int i = blockIdx.x*256 + threadIdx.x;
    if (i < 800) out[i] = woutb[i & 1];
}

// ---------------- K8: single-WG persistent LSTM scan (i8 MFMA, no inter-WG sync) ----------------
// 512 threads = 8 waves on ONE CU. Wave wv owns units [wv*32, wv*32+32) -> 128 gate cols.
// Weights live in 128 VGPRs/lane as 16x16x64 i8 B-frags. hx double-buffered in LDS i8.
// A rows replicated so row m -> batch m>>2: lane's D reg0 = its own batch, no dyn index.
__global__ __launch_bounds__(512, 2) void k_scan(const int8_t* __restrict__ Wq,
                                                 const float* __restrict__ dqs,
                                                 const float* __restrict__ biasg,
                                                 const float* __restrict__ Gperm,
                                                 const float* __restrict__ cxg,
                                                 const float* __restrict__ hxg,
                                                 const float* __restrict__ woutw,
                                                 float* __restrict__ out){
    const int tid  = threadIdx.x;
    const int wv   = tid >> 6, lane = tid & 63;
    const int q    = lane >> 4, n = lane & 15;   // q = batch; n = B col within tile

    __shared__ __align__(16) int8_t hxq[2][4*272];   // [buf][batch*272 + unit]

    // ---- preload weight B-frags: bfrag[ct][kt], ct = g*2+e over this wave's cols ----
    i32x4 bfrag[8][4];
#pragma unroll
    for (int ct=0; ct<8; ++ct)
#pragma unroll
        for (int kt=0; kt<4; ++kt)
            bfrag[ct][kt] = *(const i32x4*)(Wq +
                ((size_t)(((wv*8 + ct)*4 + kt)*4 + q)*16 + n)*16);

    // ---- per-lane elementwise identity: batch q, units ua/ub ----
    const int ua = wv*32 + n, ub = ua + 16;
    float cxa = cxg[q*256 + ua], cxb = cxg[q*256 + ub];
    const float w0a = woutw[ua], w1a = woutw[256 + ua];
    const float w0b = woutw[ub], w1b = woutw[256 + ub];
    float dqa[4], dqb[4], bba[4], bbb[4];
#pragma unroll
    for (int g=0; g<4; ++g){
        dqa[g] = dqs[g*256 + ua];   dqb[g] = dqs[g*256 + ub];
        bba[g] = biasg[g*256 + ua]; bbb[g] = biasg[g*256 + ub];
    }

    // ---- prologue: quantize initial hx into buf 0 ----
    {
        const int b0 = tid >> 7, u0 = tid & 127;
        hxq[0][b0*272 + u0]       = q8(hxg[b0*256 + u0]       * 127.0f);
        hxq[0][b0*272 + u0 + 128] = q8(hxg[b0*256 + u0 + 128] * 127.0f);
    }
    __syncthreads();

    for (int t=0; t<TT; ++t){
        // prefetch Gperm slice (consumed after MFMA)
        float ga[4], gb[4];
        {
            const float* gsrc = Gperm + ((size_t)(t*4) + q)*1024;
#pragma unroll
            for (int g=0; g<4; ++g){ ga[g] = gsrc[g*256 + ua]; gb[g] = gsrc[g*256 + ub]; }
        }
        // A-frags: row m -> batch m>>2 (4-lane broadcast reads, conflict-free)
        const int8_t* hb = hxq[t & 1];
        i32x4 afr[4];
#pragma unroll
        for (int kt=0; kt<4; ++kt)
            afr[kt] = *(const i32x4*)(hb + (n >> 2)*272 + kt*64 + q*16);

        i32x4 acc[8];
#pragma unroll
        for (int ct=0; ct<8; ++ct){ acc[ct][0]=0; acc[ct][1]=0; acc[ct][2]=0; acc[ct][3]=0; }
#pragma unroll
        for (int ct=0; ct<8; ++ct)
#pragma unroll
            for (int kt=0; kt<4; ++kt)
                acc[ct] = __builtin_amdgcn_mfma_i32_16x16x64_i8(afr[kt], bfrag[ct][kt], acc[ct], 0, 0, 0);

        // all 4 regs of every acc are this lane's batch q (replicated rows) -> use reg 0.
        // unit a: e=0 -> ct = g*2 ; unit b: e=1 -> ct = g*2+1
        float gia = (float)acc[0][0]*dqa[0] + ga[0] + bba[0];
        float gfa = (float)acc[2][0]*dqa[1] + ga[1] + bba[1];
        float gga = (float)acc[4][0]*dqa[2] + ga[2] + bba[2];
        float goa = (float)acc[6][0]*dqa[3] + ga[3] + bba[3];
        float gib = (float)acc[1][0]*dqb[0] + gb[0] + bbb[0];
        float gfb = (float)acc[3][0]*dqb[1] + gb[1] + bbb[1];
        float ggb = (float)acc[5][0]*dqb[2] + gb[2] + bbb[2];
        float gob = (float)acc[7][0]*dqb[3] + gb[3] + bbb[3];

        float cna = sigm(gfa)*cxa + sigm(gia)*tanhf(gga);
        float hna = sigm(goa)*tanhf(cna);
        float cnb = sigm(gfb)*cxb + sigm(gib)*tanhf(ggb);
        float hnb = sigm(gob)*tanhf(cnb);
        cxa = cna; cxb = cnb;

        // publish next hx (i8) into the other buffer
        int8_t* hw = hxq[(t+1) & 1];
        hw[q*272 + ua] = q8(hna * 127.0f);
        hw[q*272 + ub] = q8(hnb * 127.0f);

        // preds: reduce over n-lanes (same batch q), fire-and-forget atomics
        float p0 = hna*w0a + hnb*w0b;
        float p1 = hna*w1a + hnb*w1b;
#pragma unroll
        for (int off=1; off<16; off<<=1){
            p0 += __shfl_xor(p0, off, 64);
            p1 += __shfl_xor(p1, off, 64);
        }
        if (n == 0){
            atomicAdd(&out[t*8 + q*2 + 0], p0);
            atomicAdd(&out[t*8 + q*2 + 1], p1);
        }
        __syncthreads();
    }
}

extern "C" void kernel_launch(void* const* d_in, const int* in_sizes, int n_in,
                              void* d_out, int out_size, void* d_ws, size_t ws_size,
                              hipStream_t stream){
    const float* cam   = (const float*)d_in[0];
    const float* convw = (const float*)d_in[1];
    const float* convb = (const float*)d_in[2];
    const float* gamma = (const float*)d_in[3];
    const float* beta  = (const float*)d_in[4];
    const float* ihw   = (const float*)d_in[5];
    const float* ihb   = (const float*)d_in[6];
    const float* icw   = (const float*)d_in[7];
    const float* icb   = (const float*)d_in[8];
    const float* ww    = (const float*)d_in[9];
    const float* wb    = (const float*)d_in[10];
    const float* wattn = (const float*)d_in[11];
    // d_in[12] = wattn_b: unused (softmax is shift-invariant)
    const float* wih   = (const float*)d_in[13];
    const float* whh   = (const float*)d_in[14];
    const float* bih   = (const float*)d_in[15];
    const float* bhh   = (const float*)d_in[16];
    const float* woutw = (const float*)d_in[17];
    const float* woutb = (const float*)d_in[18];
    float* out = (float*)d_out;

    char* wsb = (char*)d_ws;
    size_t off = 0;
    auto alloc = [&](size_t bytes)->void*{
        void* p = wsb + off; off += (bytes + 255) & ~(size_t)255; return p;
    };
    unsigned short* y    = (unsigned short*)alloc((size_t)NF*FRAME*2);
    unsigned short* wr2  = (unsigned short*)alloc((size_t)589824*2);
    int8_t* Wq      = (int8_t*)alloc((size_t)262144);
    float* dqs      = (float*)alloc(1024*4);
    float* scale    = (float*)alloc(256*4);
    float* shift    = (float*)alloc(256*4);
    float* x0g      = (float*)alloc(1024*4);
    float* ctx_f    = (float*)alloc((size_t)NF*256*4);
    float* Gperm    = (float*)alloc((size_t)NF*1024*4);
    float* biasg    = (float*)alloc(1024*4);
    float* hxg      = (float*)alloc(1024*4);
    float* cxg      = (float*)alloc(1024*4);

    hipLaunchKernelGGL(k_zero, dim3(4), dim3(256), 0, stream, out, woutb);
    hipLaunchKernelGGL(k_reorder2, dim3(2304), dim3(256), 0, stream, convw, wr2);
    hipLaunchKernelGGL(k_conv2, dim3(4, NF), dim3(256), 0, stream, cam, wr2, convb, y);
    hipLaunchKernelGGL(k_bnstats, dim3(256), dim3(256), 0, stream, y, gamma, beta, scale, shift);
    hipLaunchKernelGGL(k_frame, dim3(NF), dim3(256), 0, stream, y, scale, shift, wattn, out, ctx_f, x0g);
    hipLaunchKernelGGL(k_wcomb, dim3(1024), dim3(256), 0, stream, wih, whh, ww, wb, bih, bhh, Wq, dqs, biasg);
    hipLaunchKernelGGL(k_gperm, dim3(NF), dim3(256), 0, stream, ctx_f, wih, Gperm);
    hipLaunchKernelGGL(k_init, dim3(8), dim3(256), 0, stream, x0g, ihw, ihb, icw, icb, hxg, cxg);
    hipLaunchKernelGGL(k_scan, dim3(1), dim3(512), 0, stream,
                       Wq, dqs, biasg, Gperm, cxg, hxg, woutw, out);
}

// Round 5
// 783.986 us; speedup vs baseline: 6.7848x; 1.0343x over previous
//
#include <hip/hip_runtime.h>
#include <hip/hip_bf16.h>
#include <stdint.h>

#define BB 4
#define TT 100
#define DD 256
#define LL 256
#define NF (BB*TT)          // 400 frames
#define FRAME (DD*LL)       // 65536 elements per frame (ch * spatial)
#define EPSB 1e-5f

typedef __bf16  bf16x8 __attribute__((ext_vector_type(8)));
typedef float   f32x4  __attribute__((ext_vector_type(4)));
typedef int     i32x4  __attribute__((ext_vector_type(4)));

__device__ __forceinline__ float bf2f(unsigned short u){
    return __uint_as_float(((unsigned int)u) << 16);
}
__device__ __forceinline__ unsigned short f2bf(float f){
    __hip_bfloat16 h = __float2bfloat16(f);
    return *reinterpret_cast<unsigned short*>(&h);
}
__device__ __forceinline__ float sigm(float x){ return 1.0f/(1.0f+expf(-x)); }
// fast versions for the scan (v_exp_f32 path); rel err ~1e-6, gates |x|<~30
__device__ __forceinline__ float fsigm(float x){ return 1.0f/(1.0f + __expf(-x)); }
__device__ __forceinline__ float ftanh(float x){
    x = fminf(fmaxf(x, -15.f), 15.f);
    float e = __expf(2.f*x);
    return (e - 1.f) / (e + 1.f);
}
__device__ __forceinline__ int8_t q8(float x){
    int v = (int)lrintf(x);
    v = v < -127 ? -127 : (v > 127 ? 127 : v);
    return (int8_t)v;
}

// W_comb col slot mapping for the single-WG scan:
// gate row r = g*256 + u ; u = wv*32 + e*16 + n (wv=wave 0..7, e=0/1, n=0..15)
// wave-local col tile ct = g*2 + e. B-frag k slot: k = kt*64 + quad*16 + j.
__device__ __forceinline__ size_t wq_off(int r, int k){
    int g = r >> 8, u = r & 255;
    int wv = u >> 5, e = (u >> 4) & 1, n = u & 15;
    int ct = g*2 + e;
    int kt = k >> 6, quad = (k >> 4) & 3, j = k & 15;
    return ((size_t)(((wv*8 + ct)*4 + kt)*4 + quad)*16 + n)*16 + j;
}

// ---------------- K0: reorder conv weights OIHW fp32 -> Wr2[tap][oc][ic] bf16 ----------------
__global__ void k_reorder2(const float* __restrict__ cw, unsigned short* __restrict__ wr){
    int idx = blockIdx.x*256 + threadIdx.x;          // 589824 total
    if (idx >= 256*256*9) return;
    int i  = idx & 255;
    int rest = idx >> 8;
    int o  = rest & 255;
    int t9 = rest >> 8;
    wr[idx] = f2bf(cw[((o<<8) + i)*9 + t9]);
}

// ---------------- K1: conv3x3 SAME + bias via MFMA implicit GEMM, bf16 y ----------------
#define XSTR 40
__global__ __launch_bounds__(256, 3) void k_conv2(const float* __restrict__ cam,
                                                  const unsigned short* __restrict__ wr,
                                                  const float* __restrict__ cb,
                                                  unsigned short* __restrict__ y){
    const int f   = blockIdx.y;
    const int oc0 = blockIdx.x * 64;
    const int tid = threadIdx.x;
    const int wv    = tid >> 6;
    const int quad  = (tid >> 4) & 3;
    const int wlane = tid & 15;

    __shared__ __align__(16) unsigned short Xl[324*XSTR];
    __shared__ __align__(16) unsigned short Al[192*XSTR];

    for (int i = tid; i < 324*XSTR/2; i += 256) ((unsigned int*)Xl)[i] = 0u;

    f32x4 acc[4][4];
#pragma unroll
    for (int mt=0; mt<4; ++mt){
        const int oc = oc0 + mt*16 + quad*4;
        f32x4 bv; bv[0]=cb[oc]; bv[1]=cb[oc+1]; bv[2]=cb[oc+2]; bv[3]=cb[oc+3];
#pragma unroll
        for (int nt=0; nt<4; ++nt) acc[mt][nt] = bv;
    }

    const int sp  = tid;
    const int spp = ((sp>>4)+1)*18 + (sp&15) + 1;
    const float* xs = cam + ((size_t)f*256)*256 + sp;

    for (int ck=0; ck<8; ++ck){
        const int c0 = ck*32;
        for (int tg=0; tg<3; ++tg){
            __syncthreads();
            if (tg == 0){
                const float* xc = xs + (size_t)c0*256;
#pragma unroll
                for (int jb=0; jb<4; ++jb){
                    unsigned int q0,q1,q2,q3;
                    {
                        float a0=xc[(jb*8+0)*256], a1=xc[(jb*8+1)*256];
                        float a2=xc[(jb*8+2)*256], a3=xc[(jb*8+3)*256];
                        float a4=xc[(jb*8+4)*256], a5=xc[(jb*8+5)*256];
                        float a6=xc[(jb*8+6)*256], a7=xc[(jb*8+7)*256];
                        q0 = (unsigned int)f2bf(a0) | ((unsigned int)f2bf(a1)<<16);
                        q1 = (unsigned int)f2bf(a2) | ((unsigned int)f2bf(a3)<<16);
                        q2 = (unsigned int)f2bf(a4) | ((unsigned int)f2bf(a5)<<16);
                        q3 = (unsigned int)f2bf(a6) | ((unsigned int)f2bf(a7)<<16);
                    }
                    uint4 qv; qv.x=q0; qv.y=q1; qv.z=q2; qv.w=q3;
                    *(uint4*)&Xl[spp*XSTR + jb*8] = qv;
                }
            }
            if (tid < 192){
                const unsigned short* src = wr +
                    ((size_t)((tg*3 + (tid>>6))*256 + oc0 + (tid&63)))*256 + c0;
                const uint4* s4 = (const uint4*)src;
                uint4* dq = (uint4*)(Al + tid*XSTR);
                dq[0]=s4[0]; dq[1]=s4[1]; dq[2]=s4[2]; dq[3]=s4[3];
            }
            __syncthreads();
#pragma unroll
            for (int cc=0; cc<3; ++cc){
                bf16x8 af[4], bfr[4];
#pragma unroll
                for (int mt=0; mt<4; ++mt)
                    af[mt] = *(const bf16x8*)(Al + ((cc*64 + mt*16 + wlane)*XSTR + quad*8));
#pragma unroll
                for (int nt=0; nt<4; ++nt){
                    const int hh = wv*4 + nt;
                    const int pp = (hh + tg)*18 + wlane + cc;
                    bfr[nt] = *(const bf16x8*)(Xl + (pp*XSTR + quad*8));
                }
#pragma unroll
                for (int mt=0; mt<4; ++mt)
#pragma unroll
                    for (int nt=0; nt<4; ++nt)
                        acc[mt][nt] = __builtin_amdgcn_mfma_f32_16x16x32_bf16(
                            af[mt], bfr[nt], acc[mt][nt], 0, 0, 0);
            }
        }
    }

#pragma unroll
    for (int mt=0; mt<4; ++mt){
        const int oc = oc0 + mt*16 + quad*4;
#pragma unroll
        for (int nt=0; nt<4; ++nt){
            const int p = (wv*4 + nt)*16 + wlane;
#pragma unroll
            for (int reg=0; reg<4; ++reg)
                y[((size_t)(f*256) + oc + reg)*256 + p] = f2bf(acc[mt][nt][reg]);
        }
    }
}

// ---------------- K2a: per-frame BN partial sums (thread = channel) ----------------
__global__ __launch_bounds__(256) void k_bnpart(const unsigned short* __restrict__ y,
                                                float* __restrict__ Sp,
                                                float* __restrict__ Sq){
    const int f = blockIdx.x, c = threadIdx.x;
    const uint4* p4 = (const uint4*)(y + (size_t)f*FRAME + c*256);
    float s = 0.f, q = 0.f;
#pragma unroll 8
    for (int j=0; j<32; ++j){
        uint4 u = p4[j];
#pragma unroll
        for (int k=0; k<4; ++k){
            unsigned int w = (&u.x)[k];
            float a = bf2f((unsigned short)(w & 0xffff));
            float b = bf2f((unsigned short)(w >> 16));
            s += a + b; q += a*a + b*b;
        }
    }
    Sp[f*256 + c] = s;
    Sq[f*256 + c] = q;
}

// ---------------- K2b: finish BN stats -> scale/shift per channel ----------------
__global__ __launch_bounds__(64) void k_bnfin(const float* __restrict__ Sp,
                                              const float* __restrict__ Sq,
                                              const float* __restrict__ gamma,
                                              const float* __restrict__ beta,
                                              float* __restrict__ scale,
                                              float* __restrict__ shift){
    const int c = blockIdx.x, lane = threadIdx.x;
    float s = 0.f, q = 0.f;
    for (int f=lane; f<NF; f+=64){ s += Sp[f*256 + c]; q += Sq[f*256 + c]; }
#pragma unroll
    for (int off=32; off; off>>=1){ s += __shfl_down(s,off,64); q += __shfl_down(q,off,64); }
    if (lane==0){
        const float invN = 1.0f/(float)(NF*256);
        float mean = s*invN;
        float var  = q*invN - mean*mean;
        float istd = rsqrtf(var + EPSB);
        float sc = gamma[c]*istd;
        scale[c] = sc;
        shift[c] = beta[c] - mean*sc;
    }
}

// ---------------- K3: per-frame fdot -> softmax -> alpha/logp out, ctx_f, x0 ----------------
__global__ __launch_bounds__(256) void k_frame(const unsigned short* __restrict__ y,
                                               const float* __restrict__ scale,
                                               const float* __restrict__ shift,
                                               const float* __restrict__ wattn,
                                               float* __restrict__ d_out,
                                               float* __restrict__ ctx_f,
                                               float* __restrict__ x0g){
    const int f = blockIdx.x, tid = threadIdx.x;
    const int b = f / TT, t = f - b*TT;
    const int wave = tid>>6, lane = tid&63;
    __shared__ float fdotL[256], alphaL[256], x0acc[256], wattnL[256];
    __shared__ float redM[4], redS[4];
    wattnL[tid] = wattn[tid];
    x0acc[tid] = 0.f;
    __syncthreads();
    const bool isT0 = (t==0);
    const float wl0 = wattnL[lane*4+0], wl1 = wattnL[lane*4+1];
    const float wl2 = wattnL[lane*4+2], wl3 = wattnL[lane*4+3];
    const ushort4* y4 = (const ushort4*)(y + (size_t)f*FRAME);
    for (int ci=0; ci<64; ++ci){
        int c = wave + ci*4;
        ushort4 u = y4[c*64 + lane];
        float sc = scale[c], sh = shift[c];
        float v0 = fmaxf(fmaf(bf2f(u.x),sc,sh),0.f);
        float v1 = fmaxf(fmaf(bf2f(u.y),sc,sh),0.f);
        float v2 = fmaxf(fmaf(bf2f(u.z),sc,sh),0.f);
        float v3 = fmaxf(fmaf(bf2f(u.w),sc,sh),0.f);
        float s = v0*wl0 + v1*wl1 + v2*wl2 + v3*wl3;
#pragma unroll
        for (int off=32; off; off>>=1) s += __shfl_down(s,off,64);
        if (lane==0) fdotL[c] = s;
        if (isT0){
            atomicAdd(&x0acc[lane*4+0], v0);
            atomicAdd(&x0acc[lane*4+1], v1);
            atomicAdd(&x0acc[lane*4+2], v2);
            atomicAdd(&x0acc[lane*4+3], v3);
        }
    }
    __syncthreads();
    float v = fdotL[tid];
    float m = v;
#pragma unroll
    for (int off=32; off; off>>=1) m = fmaxf(m, __shfl_down(m,off,64));
    if (lane==0) redM[wave]=m;
    __syncthreads();
    m = fmaxf(fmaxf(redM[0],redM[1]),fmaxf(redM[2],redM[3]));
    float e = expf(v-m);
    float ss = e;
#pragma unroll
    for (int off=32; off; off>>=1) ss += __shfl_down(ss,off,64);
    if (lane==0) redS[wave]=ss;
    __syncthreads();
    float S = redS[0]+redS[1]+redS[2]+redS[3];
    float logS = logf(S);
    float alpha = e / S;
    d_out[800    + ((t*BB)+b)*256 + tid] = alpha;
    d_out[103200 + ((t*BB)+b)*256 + tid] = v - m - logS;
    alphaL[tid] = alpha;
    if (isT0) x0g[b*256+tid] = x0acc[tid];
    __syncthreads();
    const unsigned short* yf = y + (size_t)f*FRAME;
    float ctx = 0.f;
    for (int c=0;c<256;++c){
        float yv = fmaxf(fmaf(bf2f(yf[c*256+tid]), scale[c], shift[c]), 0.f);
        ctx = fmaf(yv, alphaL[c], ctx);
    }
    ctx_f[f*256+tid] = ctx;
}

// ---------------- K4: Gp packed in scan-thread order ----------------
// scan thread tid = wv*64 + b*16 + n reads float4 pair at Gp[t*4096 + tid*8].
// row r = g*256 + u, u = wv*32 + e*16 + n  ->  slot = e*4 + g.
__global__ __launch_bounds__(256) void k_gperm(const float* __restrict__ ctx_f,
                                               const float* __restrict__ wih,
                                               float* __restrict__ Gp){
    const int f = blockIdx.x, tid = threadIdx.x;
    const int b = f / TT, t = f - b*TT;
    __shared__ float ctxL[256];
    ctxL[tid] = ctx_f[f*256+tid];
    __syncthreads();
    const int wave = tid>>6, lane = tid&63;
    const float4* c4 = (const float4*)ctxL;
    float4 cv = c4[lane];
    const float4* w4 = (const float4*)wih;
    float* gout = Gp + (size_t)t*4096;
    for (int r=wave; r<1024; r+=4){
        float4 wv = w4[r*64 + lane];
        float s = cv.x*wv.x + cv.y*wv.y + cv.z*wv.z + cv.w*wv.w;
#pragma unroll
        for (int off=32; off; off>>=1) s += __shfl_down(s,off,64);
        if (lane==0){
            int g = r >> 8, u = r & 255;
            int wvv = u >> 5, e = (u >> 4) & 1, nn = u & 15;
            gout[(wvv*64 + b*16 + nn)*8 + e*4 + g] = s;
        }
    }
}

// ---------------- K5: W_comb = whh + wih@w_w -> int8 frag-packed + per-row dq scale ----------------
__global__ __launch_bounds__(256) void k_wcomb(const float* __restrict__ wih,
                                               const float* __restrict__ whh,
                                               const float* __restrict__ ww,
                                               const float* __restrict__ wb,
                                               const float* __restrict__ bih,
                                               const float* __restrict__ bhh,
                                               int8_t* __restrict__ Wq,
                                               float* __restrict__ dqs,
                                               float* __restrict__ biasg){
    const int r = blockIdx.x, tid = threadIdx.x;
    const int lane = tid&63, wave = tid>>6;
    __shared__ float wihL[256];
    __shared__ float red[4];
    __shared__ float smaxs;
    wihL[tid] = wih[r*256+tid];
    __syncthreads();
    float acc = whh[r*256+tid];
    for (int k=0;k<256;++k) acc = fmaf(wihL[k], ww[k*256+tid], acc);
    float m = fabsf(acc);
#pragma unroll
    for (int off=32; off; off>>=1) m = fmaxf(m, __shfl_down(m,off,64));
    if (lane==0) red[wave] = m;
    __syncthreads();
    if (tid==0){
        float s = fmaxf(fmaxf(red[0],red[1]),fmaxf(red[2],red[3]));
        smaxs = (s > 1e-30f) ? s : 1.0f;
        dqs[r] = smaxs * (1.0f/16129.0f);   // smax/(127*127)
    }
    __syncthreads();
    float inv = 127.0f / smaxs;
    Wq[wq_off(r, tid)] = q8(acc * inv);
    if (tid < 64){
        float s = 0.f;
#pragma unroll
        for (int q=0;q<4;++q) s += wihL[tid + 64*q] * wb[tid + 64*q];
#pragma unroll
        for (int off=32; off; off>>=1) s += __shfl_down(s,off,64);
        if (tid==0) biasg[r] = bih[r] + bhh[r] + s;
    }
}

// ---------------- K6: initial hx/cx = tanh(x0 @ W.T + b); block 0 also inits preds ----------------
__global__ __launch_bounds__(256) void k_init(const float* __restrict__ x0g,
                                              const float* __restrict__ ihw,
                                              const float* __restrict__ ihb,
                                              const float* __restrict__ icw,
                                              const float* __restrict__ icb,
                                              float* __restrict__ hxg,
                                              float* __restrict__ cxg,
                                              float* __restrict__ out,
                                              const float* __restrict__ woutb){
    const int b = blockIdx.x >> 1, which = blockIdx.x & 1;
    const int tid = threadIdx.x, wave = tid>>6, lane = tid&63;
    if (blockIdx.x == 0){
        for (int i=tid; i<800; i+=256) out[i] = woutb[i & 1];
    }
    __shared__ float xL[256];
    xL[tid] = x0g[b*256+tid] * (1.0f/256.0f);
    __syncthreads();
    const float* wmat = which ? icw : ihw;
    const float* bias = which ? icb : ihb;
    float* dst = which ? cxg : hxg;
    const float4* x4 = (const float4*)xL;
    float4 xv = x4[lane];
    const float4* w4 = (const float4*)wmat;
    for (int r=wave; r<256; r+=4){
        float4 wv = w4[r*64+lane];
        float s = xv.x*wv.x + xv.y*wv.y + xv.z*wv.z + xv.w*wv.w;
#pragma unroll
        for (int off=32; off; off>>=1) s += __shfl_down(s,off,64);
        if (lane==0) dst[b*256+r] = tanhf(s + bias[r]);
    }
}

// ---------------- K8: single-WG persistent LSTM scan (i8 MFMA, fast transcendentals) ----------------
__global__ __launch_bounds__(512, 2) void k_scan(const int8_t* __restrict__ Wq,
                                                 const float* __restrict__ dqs,
                                                 const float* __restrict__ biasg,
                                                 const float* __restrict__ Gp,
                                                 const float* __restrict__ cxg,
                                                 const float* __restrict__ hxg,
                                                 const float* __restrict__ woutw,
                                                 float* __restrict__ out){
    const int tid  = threadIdx.x;
    const int wv   = tid >> 6, lane = tid & 63;
    const int q    = lane >> 4, n = lane & 15;   // q = batch; n = B col within tile

    __shared__ __align__(16) int8_t hxq[2][4*272];   // [buf][batch*272 + unit]

    // ---- preload weight B-frags ----
    i32x4 bfrag[8][4];
#pragma unroll
    for (int ct=0; ct<8; ++ct)
#pragma unroll
        for (int kt=0; kt<4; ++kt)
            bfrag[ct][kt] = *(const i32x4*)(Wq +
                ((size_t)(((wv*8 + ct)*4 + kt)*4 + q)*16 + n)*16);

    // ---- per-lane elementwise identity: batch q, units ua/ub ----
    const int ua = wv*32 + n, ub = ua + 16;
    float cxa = cxg[q*256 + ua], cxb = cxg[q*256 + ub];
    const float w0a = woutw[ua], w1a = woutw[256 + ua];
    const float w0b = woutw[ub], w1b = woutw[256 + ub];
    float dqa[4], dqb[4], bba[4], bbb[4];
#pragma unroll
    for (int g=0; g<4; ++g){
        dqa[g] = dqs[g*256 + ua];   dqb[g] = dqs[g*256 + ub];
        bba[g] = biasg[g*256 + ua]; bbb[g] = biasg[g*256 + ub];
    }

    // ---- prologue: quantize initial hx into buf 0 ----
    {
        const int b0 = tid >> 7, u0 = tid & 127;
        hxq[0][b0*272 + u0]       = q8(hxg[b0*256 + u0]       * 127.0f);
        hxq[0][b0*272 + u0 + 128] = q8(hxg[b0*256 + u0 + 128] * 127.0f);
    }
    __syncthreads();

    for (int t=0; t<TT; ++t){
        // prefetch packed gate biases: 2 x dwordx4 per thread
        const float4* gp4 = (const float4*)(Gp + (size_t)t*4096 + tid*8);
        float4 gA = gp4[0], gB = gp4[1];

        const int8_t* hb = hxq[t & 1];
        i32x4 afr[4];
#pragma unroll
        for (int kt=0; kt<4; ++kt)
            afr[kt] = *(const i32x4*)(hb + (n >> 2)*272 + kt*64 + q*16);

        i32x4 acc[8];
#pragma unroll
        for (int ct=0; ct<8; ++ct){ acc[ct][0]=0; acc[ct][1]=0; acc[ct][2]=0; acc[ct][3]=0; }
#pragma unroll
        for (int ct=0; ct<8; ++ct)
#pragma unroll
            for (int kt=0; kt<4; ++kt)
                acc[ct] = __builtin_amdgcn_mfma_i32_16x16x64_i8(afr[kt], bfrag[ct][kt], acc[ct], 0, 0, 0);

        float gia = (float)acc[0][0]*dqa[0] + gA.x + bba[0];
        float gfa = (float)acc[2][0]*dqa[1] + gA.y + bba[1];
        float gga = (float)acc[4][0]*dqa[2] + gA.z + bba[2];
        float goa = (float)acc[6][0]*dqa[3] + gA.w + bba[3];
        float gib = (float)acc[1][0]*dqb[0] + gB.x + bbb[0];
        float gfb = (float)acc[3][0]*dqb[1] + gB.y + bbb[1];
        float ggb = (float)acc[5][0]*dqb[2] + gB.z + bbb[2];
        float gob = (float)acc[7][0]*dqb[3] + gB.w + bbb[3];

        float cna = fsigm(gfa)*cxa + fsigm(gia)*ftanh(gga);
        float hna = fsigm(goa)*ftanh(cna);
        float cnb = fsigm(gfb)*cxb + fsigm(gib)*ftanh(ggb);
        float hnb = fsigm(gob)*ftanh(cnb);
        cxa = cna; cxb = cnb;

        int8_t* hw = hxq[(t+1) & 1];
        hw[q*272 + ua] = q8(hna * 127.0f);
        hw[q*272 + ub] = q8(hnb * 127.0f);

        float p0 = hna*w0a + hnb*w0b;
        float p1 = hna*w1a + hnb*w1b;
#pragma unroll
        for (int off=1; off<16; off<<=1){
            p0 += __shfl_xor(p0, off, 64);
            p1 += __shfl_xor(p1, off, 64);
        }
        if (n == 0){
            atomicAdd(&out[t*8 + q*2 + 0], p0);
            atomicAdd(&out[t*8 + q*2 + 1], p1);
        }
        __syncthreads();
    }
}

extern "C" void kernel_launch(void* const* d_in, const int* in_sizes, int n_in,
                              void* d_out, int out_size, void* d_ws, size_t ws_size,
                              hipStream_t stream){
    const float* cam   = (const float*)d_in[0];
    const float* convw = (const float*)d_in[1];
    const float* convb = (const float*)d_in[2];
    const float* gamma = (const float*)d_in[3];
    const float* beta  = (const float*)d_in[4];
    const float* ihw   = (const float*)d_in[5];
    const float* ihb   = (const float*)d_in[6];
    const float* icw   = (const float*)d_in[7];
    const float* icb   = (const float*)d_in[8];
    const float* ww    = (const float*)d_in[9];
    const float* wb    = (const float*)d_in[10];
    const float* wattn = (const float*)d_in[11];
    // d_in[12] = wattn_b: unused (softmax is shift-invariant)
    const float* wih   = (const float*)d_in[13];
    const float* whh   = (const float*)d_in[14];
    const float* bih   = (const float*)d_in[15];
    const float* bhh   = (const float*)d_in[16];
    const float* woutw = (const float*)d_in[17];
    const float* woutb = (const float*)d_in[18];
    float* out = (float*)d_out;

    char* wsb = (char*)d_ws;
    size_t off = 0;
    auto alloc = [&](size_t bytes)->void*{
        void* p = wsb + off; off += (bytes + 255) & ~(size_t)255; return p;
    };
    unsigned short* y    = (unsigned short*)alloc((size_t)NF*FRAME*2);
    unsigned short* wr2  = (unsigned short*)alloc((size_t)589824*2);
    int8_t* Wq      = (int8_t*)alloc((size_t)262144);
    float* dqs      = (float*)alloc(1024*4);
    float* Sp       = (float*)alloc((size_t)NF*256*4);
    float* Sq       = (float*)alloc((size_t)NF*256*4);
    float* scale    = (float*)alloc(256*4);
    float* shift    = (float*)alloc(256*4);
    float* x0g      = (float*)alloc(1024*4);
    float* ctx_f    = (float*)alloc((size_t)NF*256*4);
    float* Gp       = (float*)alloc((size_t)TT*4096*4);
    float* biasg    = (float*)alloc(1024*4);
    float* hxg      = (float*)alloc(1024*4);
    float* cxg      = (float*)alloc(1024*4);

    hipLaunchKernelGGL(k_reorder2, dim3(2304), dim3(256), 0, stream, convw, wr2);
    hipLaunchKernelGGL(k_conv2, dim3(4, NF), dim3(256), 0, stream, cam, wr2, convb, y);
    hipLaunchKernelGGL(k_bnpart, dim3(NF), dim3(256), 0, stream, y, Sp, Sq);
    hipLaunchKernelGGL(k_bnfin, dim3(256), dim3(64), 0, stream, Sp, Sq, gamma, beta, scale, shift);
    hipLaunchKernelGGL(k_frame, dim3(NF), dim3(256), 0, stream, y, scale, shift, wattn, out, ctx_f, x0g);
    hipLaunchKernelGGL(k_wcomb, dim3(1024), dim3(256), 0, stream, wih, whh, ww, wb, bih, bhh, Wq, dqs, biasg);
    hipLaunchKernelGGL(k_gperm, dim3(NF), dim3(256), 0, stream, ctx_f, wih, Gp);
    hipLaunchKernelGGL(k_init, dim3(8), dim3(256), 0, stream, x0g, ihw, ihb, icw, icb, hxg, cxg, out, woutb);
    hipLaunchKernelGGL(k_scan, dim3(1), dim3(512), 0, stream,
                       Wq, dqs, biasg, Gp, cxg, hxg, woutw, out);
}

// Round 7
// 742.886 us; speedup vs baseline: 7.1602x; 1.0553x over previous
//
#include <hip/hip_runtime.h>
#include <hip/hip_bf16.h>
#include <stdint.h>

#define BB 4
#define TT 100
#define DD 256
#define LL 256
#define NF (BB*TT)          // 400 frames
#define FRAME (DD*LL)       // 65536 elements per frame (ch * spatial)
#define EPSB 1e-5f

#define S1_N 2304           // k_prep: wr2 reorder blocks
#define S2_N 1024           // k_prep: wcomb rows

typedef __bf16  bf16x8 __attribute__((ext_vector_type(8)));
typedef float   f32x4  __attribute__((ext_vector_type(4)));
typedef int     i32x4  __attribute__((ext_vector_type(4)));

__device__ __forceinline__ float bf2f(unsigned short u){
    return __uint_as_float(((unsigned int)u) << 16);
}
__device__ __forceinline__ unsigned short f2bf(float f){
    __hip_bfloat16 h = __float2bfloat16(f);
    return *reinterpret_cast<unsigned short*>(&h);
}
__device__ __forceinline__ float fsigm(float x){ return 1.0f/(1.0f + __expf(-x)); }
__device__ __forceinline__ float ftanh(float x){
    x = fminf(fmaxf(x, -15.f), 15.f);
    float e = __expf(2.f*x);
    return (e - 1.f) / (e + 1.f);
}
__device__ __forceinline__ int8_t q8(float x){
    int v = (int)lrintf(x);
    v = v < -127 ? -127 : (v > 127 ? 127 : v);
    return (int8_t)v;
}

// scan W_comb col slot mapping: gate row r=g*256+u; u=wv*32+e*16+n; ct=g*2+e
__device__ __forceinline__ size_t wq_off(int r, int k){
    int g = r >> 8, u = r & 255;
    int wv = u >> 5, e = (u >> 4) & 1, n = u & 15;
    int ct = g*2 + e;
    int kt = k >> 6, quad = (k >> 4) & 3, j = k & 15;
    return ((size_t)(((wv*8 + ct)*4 + kt)*4 + quad)*16 + n)*16 + j;
}

// ================= K_PREP: fused wr2-reorder + wcomb-quant + pred-bias init =================
__global__ __launch_bounds__(256) void k_prep(const float* __restrict__ convw,
                                              const float* __restrict__ wih,
                                              const float* __restrict__ whh,
                                              const float* __restrict__ ww,
                                              const float* __restrict__ wb,
                                              const float* __restrict__ bih,
                                              const float* __restrict__ bhh,
                                              const float* __restrict__ woutb,
                                              unsigned short* __restrict__ wr2,
                                              int8_t* __restrict__ Wq,
                                              float* __restrict__ dqs,
                                              float* __restrict__ biasg,
                                              float* __restrict__ out){
    const int bid = blockIdx.x, tid = threadIdx.x;
    __shared__ float wihL[256];
    __shared__ float red[4];
    __shared__ float smaxs;
    if (bid < S1_N){
        // wr2[tap][oc][ic] bf16 from convw OIHW fp32
        int idx = bid*256 + tid;                 // 0..589823
        int i  = idx & 255;
        int rest = idx >> 8;
        int o  = rest & 255;
        int t9 = rest >> 8;
        wr2[idx] = f2bf(convw[((o<<8) + i)*9 + t9]);
    } else if (bid < S1_N + S2_N){
        // W_comb = whh + wih@w_w -> int8 frag-packed, dq scales, fused bias
        const int r = bid - S1_N;
        const int lane = tid&63, wave = tid>>6;
        wihL[tid] = wih[r*256+tid];
        __syncthreads();
        float acc = whh[r*256+tid];
        for (int k=0;k<256;++k) acc = fmaf(wihL[k], ww[k*256+tid], acc);
        float m = fabsf(acc);
#pragma unroll
        for (int off=32; off; off>>=1) m = fmaxf(m, __shfl_down(m,off,64));
        if (lane==0) red[wave] = m;
        __syncthreads();
        if (tid==0){
            float s = fmaxf(fmaxf(red[0],red[1]),fmaxf(red[2],red[3]));
            smaxs = (s > 1e-30f) ? s : 1.0f;
            dqs[r] = smaxs * (1.0f/16129.0f);    // smax/(127*127)
        }
        __syncthreads();
        float inv = 127.0f / smaxs;
        Wq[wq_off(r, tid)] = q8(acc * inv);
        if (tid < 64){
            float s = 0.f;
#pragma unroll
            for (int q=0;q<4;++q) s += wihL[tid + 64*q] * wb[tid + 64*q];
#pragma unroll
            for (int off=32; off; off>>=1) s += __shfl_down(s,off,64);
            if (tid==0) biasg[r] = bih[r] + bhh[r] + s;
        }
    } else {
        for (int i=tid; i<800; i+=256) out[i] = woutb[i & 1];
    }
}

// ================= K_CONV2: conv3x3 via MFMA + fused BN partials =================
// grid (4, 400): oc group x frame. 256 threads = 4 waves. (proven R2-R5 structure)
#define XSTR 40
__global__ __launch_bounds__(256, 3) void k_conv2(const float* __restrict__ cam,
                                                  const unsigned short* __restrict__ wr,
                                                  const float* __restrict__ cb,
                                                  unsigned short* __restrict__ y,
                                                  float* __restrict__ Sp,
                                                  float* __restrict__ Sq){
    const int f   = blockIdx.y;
    const int oc0 = blockIdx.x * 64;
    const int tid = threadIdx.x;
    const int wv    = tid >> 6;
    const int quad  = (tid >> 4) & 3;
    const int wlane = tid & 15;

    __shared__ __align__(16) unsigned short Xl[324*XSTR];
    __shared__ __align__(16) unsigned short Al[192*XSTR];
    __shared__ float SredS[64], SredQ[64];

    for (int i = tid; i < 324*XSTR/2; i += 256) ((unsigned int*)Xl)[i] = 0u;
    if (tid < 64){ SredS[tid]=0.f; SredQ[tid]=0.f; }

    f32x4 acc[4][4];
#pragma unroll
    for (int mt=0; mt<4; ++mt){
        const int oc = oc0 + mt*16 + quad*4;
        f32x4 bv; bv[0]=cb[oc]; bv[1]=cb[oc+1]; bv[2]=cb[oc+2]; bv[3]=cb[oc+3];
#pragma unroll
        for (int nt=0; nt<4; ++nt) acc[mt][nt] = bv;
    }

    const int sp  = tid;
    const int spp = ((sp>>4)+1)*18 + (sp&15) + 1;
    const float* xs = cam + ((size_t)f*256)*256 + sp;

    for (int ck=0; ck<8; ++ck){
        const int c0 = ck*32;
        for (int tg=0; tg<3; ++tg){
            __syncthreads();
            if (tg == 0){
                const float* xc = xs + (size_t)c0*256;
#pragma unroll
                for (int jb=0; jb<4; ++jb){
                    unsigned int q0,q1,q2,q3;
                    {
                        float a0=xc[(jb*8+0)*256], a1=xc[(jb*8+1)*256];
                        float a2=xc[(jb*8+2)*256], a3=xc[(jb*8+3)*256];
                        float a4=xc[(jb*8+4)*256], a5=xc[(jb*8+5)*256];
                        float a6=xc[(jb*8+6)*256], a7=xc[(jb*8+7)*256];
                        q0 = (unsigned int)f2bf(a0) | ((unsigned int)f2bf(a1)<<16);
                        q1 = (unsigned int)f2bf(a2) | ((unsigned int)f2bf(a3)<<16);
                        q2 = (unsigned int)f2bf(a4) | ((unsigned int)f2bf(a5)<<16);
                        q3 = (unsigned int)f2bf(a6) | ((unsigned int)f2bf(a7)<<16);
                    }
                    uint4 qv; qv.x=q0; qv.y=q1; qv.z=q2; qv.w=q3;
                    *(uint4*)&Xl[spp*XSTR + jb*8] = qv;
                }
            }
            if (tid < 192){
                const unsigned short* src = wr +
                    ((size_t)((tg*3 + (tid>>6))*256 + oc0 + (tid&63)))*256 + c0;
                const uint4* s4 = (const uint4*)src;
                uint4* dq = (uint4*)(Al + tid*XSTR);
                dq[0]=s4[0]; dq[1]=s4[1]; dq[2]=s4[2]; dq[3]=s4[3];
            }
            __syncthreads();
#pragma unroll
            for (int cc=0; cc<3; ++cc){
                bf16x8 af[4], bfr[4];
#pragma unroll
                for (int mt=0; mt<4; ++mt)
                    af[mt] = *(const bf16x8*)(Al + ((cc*64 + mt*16 + wlane)*XSTR + quad*8));
#pragma unroll
                for (int nt=0; nt<4; ++nt){
                    const int hh = wv*4 + nt;
                    const int pp = (hh + tg)*18 + wlane + cc;
                    bfr[nt] = *(const bf16x8*)(Xl + (pp*XSTR + quad*8));
                }
#pragma unroll
                for (int mt=0; mt<4; ++mt)
#pragma unroll
                    for (int nt=0; nt<4; ++nt)
                        acc[mt][nt] = __builtin_amdgcn_mfma_f32_16x16x32_bf16(
                            af[mt], bfr[nt], acc[mt][nt], 0, 0, 0);
            }
        }
    }

    // epilogue: y store (C/D layout col=lane&15, row=(lane>>4)*4+reg) [m89-verified]
#pragma unroll
    for (int mt=0; mt<4; ++mt){
        const int oc = oc0 + mt*16 + quad*4;
#pragma unroll
        for (int nt=0; nt<4; ++nt){
            const int p = (wv*4 + nt)*16 + wlane;
#pragma unroll
            for (int reg=0; reg<4; ++reg)
                y[((size_t)(f*256) + oc + reg)*256 + p] = f2bf(acc[mt][nt][reg]);
        }
    }
    // fused BN partial sums: per-(f,oc) sum over 256 spatial
    __syncthreads();
#pragma unroll
    for (int mt=0; mt<4; ++mt){
#pragma unroll
        for (int reg=0; reg<4; ++reg){
            float s=0.f, q=0.f;
#pragma unroll
            for (int nt=0; nt<4; ++nt){ float v=acc[mt][nt][reg]; s+=v; q+=v*v; }
#pragma unroll
            for (int off=1; off<16; off<<=1){ s += __shfl_xor(s,off,64); q += __shfl_xor(q,off,64); }
            if (wlane==0){
                atomicAdd(&SredS[mt*16 + quad*4 + reg], s);
                atomicAdd(&SredQ[mt*16 + quad*4 + reg], q);
            }
        }
    }
    __syncthreads();
    if (tid < 64){
        Sp[f*256 + oc0 + tid] = SredS[tid];
        Sq[f*256 + oc0 + tid] = SredQ[tid];
    }
}

// ================= K_BNFIN: finish BN stats -> scale/shift =================
__global__ __launch_bounds__(64) void k_bnfin(const float* __restrict__ Sp,
                                              const float* __restrict__ Sq,
                                              const float* __restrict__ gamma,
                                              const float* __restrict__ beta,
                                              float* __restrict__ scale,
                                              float* __restrict__ shift){
    const int c = blockIdx.x, lane = threadIdx.x;
    float s = 0.f, q = 0.f;
    for (int f=lane; f<NF; f+=64){ s += Sp[f*256 + c]; q += Sq[f*256 + c]; }
#pragma unroll
    for (int off=32; off; off>>=1){ s += __shfl_down(s,off,64); q += __shfl_down(q,off,64); }
    if (lane==0){
        const float invN = 1.0f/(float)(NF*256);
        float mean = s*invN;
        float var  = q*invN - mean*mean;
        float istd = rsqrtf(var + EPSB);
        float sc = gamma[c]*istd;
        scale[c] = sc;
        shift[c] = beta[c] - mean*sc;
    }
}

// ================= K_FRAME2: softmax/alpha/logp + ctx + x0 + fused Gp build =================
__global__ __launch_bounds__(256) void k_frame2(const unsigned short* __restrict__ y,
                                                const float* __restrict__ scale,
                                                const float* __restrict__ shift,
                                                const float* __restrict__ wattn,
                                                const float* __restrict__ wih,
                                                float* __restrict__ d_out,
                                                float* __restrict__ Gp,
                                                float* __restrict__ x0g){
    const int f = blockIdx.x, tid = threadIdx.x;
    const int b = f / TT, t = f - b*TT;
    const int wave = tid>>6, lane = tid&63;
    __shared__ float fdotL[256], alphaL[256], x0acc[256], wattnL[256];
    __shared__ float redM[4], redS[4];
    wattnL[tid] = wattn[tid];
    x0acc[tid] = 0.f;
    __syncthreads();
    const bool isT0 = (t==0);
    const float wl0 = wattnL[lane*4+0], wl1 = wattnL[lane*4+1];
    const float wl2 = wattnL[lane*4+2], wl3 = wattnL[lane*4+3];
    const ushort4* y4 = (const ushort4*)(y + (size_t)f*FRAME);
    for (int ci=0; ci<64; ++ci){
        int c = wave + ci*4;
        ushort4 u = y4[c*64 + lane];
        float sc = scale[c], sh = shift[c];
        float v0 = fmaxf(fmaf(bf2f(u.x),sc,sh),0.f);
        float v1 = fmaxf(fmaf(bf2f(u.y),sc,sh),0.f);
        float v2 = fmaxf(fmaf(bf2f(u.z),sc,sh),0.f);
        float v3 = fmaxf(fmaf(bf2f(u.w),sc,sh),0.f);
        float s = v0*wl0 + v1*wl1 + v2*wl2 + v3*wl3;
#pragma unroll
        for (int off=32; off; off>>=1) s += __shfl_down(s,off,64);
        if (lane==0) fdotL[c] = s;
        if (isT0){
            atomicAdd(&x0acc[lane*4+0], v0);
            atomicAdd(&x0acc[lane*4+1], v1);
            atomicAdd(&x0acc[lane*4+2], v2);
            atomicAdd(&x0acc[lane*4+3], v3);
        }
    }
    __syncthreads();
    float v = fdotL[tid];
    float m = v;
#pragma unroll
    for (int off=32; off; off>>=1) m = fmaxf(m, __shfl_down(m,off,64));
    if (lane==0) redM[wave]=m;
    __syncthreads();
    m = fmaxf(fmaxf(redM[0],redM[1]),fmaxf(redM[2],redM[3]));
    float e = __expf(v-m);
    float ss = e;
#pragma unroll
    for (int off=32; off; off>>=1) ss += __shfl_down(ss,off,64);
    if (lane==0) redS[wave]=ss;
    __syncthreads();
    float S = redS[0]+redS[1]+redS[2]+redS[3];
    float logS = logf(S);
    float alpha = e / S;
    d_out[800    + ((t*BB)+b)*256 + tid] = alpha;
    d_out[103200 + ((t*BB)+b)*256 + tid] = v - m - logS;
    alphaL[tid] = alpha;
    if (isT0) x0g[b*256+tid] = x0acc[tid];
    __syncthreads();
    // ctx[d] = sum_c feats[c,d]*alpha[c]
    const unsigned short* yf = y + (size_t)f*FRAME;
    float ctx = 0.f;
    for (int c=0;c<256;++c){
        float yv = fmaxf(fmaf(bf2f(yf[c*256+tid]), scale[c], shift[c]), 0.f);
        ctx = fmaf(yv, alphaL[c], ctx);
    }
    __syncthreads();
    fdotL[tid] = ctx;
    __syncthreads();
    // fused gperm: Gp packed in scan-thread order; slot = e*4 + g
    const float4* c4 = (const float4*)fdotL;
    float4 cv = c4[lane];
    const float4* w4 = (const float4*)wih;
    float* gout = Gp + (size_t)t*4096;
    for (int r=wave; r<1024; r+=4){
        float4 wv = w4[r*64 + lane];
        float s = cv.x*wv.x + cv.y*wv.y + cv.z*wv.z + cv.w*wv.w;
#pragma unroll
        for (int off=32; off; off>>=1) s += __shfl_down(s,off,64);
        if (lane==0){
            int g = r >> 8, u = r & 255;
            int wvv = u >> 5, e = (u >> 4) & 1, nn = u & 15;
            gout[(wvv*64 + b*16 + nn)*8 + e*4 + g] = s;
        }
    }
}

// ================= K_INIT: hx/cx = tanh(x0 @ W.T + b) =================
__global__ __launch_bounds__(256) void k_init(const float* __restrict__ x0g,
                                              const float* __restrict__ ihw,
                                              const float* __restrict__ ihb,
                                              const float* __restrict__ icw,
                                              const float* __restrict__ icb,
                                              float* __restrict__ hxg,
                                              float* __restrict__ cxg){
    const int b = blockIdx.x >> 1, which = blockIdx.x & 1;
    const int tid = threadIdx.x, wave = tid>>6, lane = tid&63;
    __shared__ float xL[256];
    xL[tid] = x0g[b*256+tid] * (1.0f/256.0f);
    __syncthreads();
    const float* wmat = which ? icw : ihw;
    const float* bias = which ? icb : ihb;
    float* dst = which ? cxg : hxg;
    const float4* x4 = (const float4*)xL;
    float4 xv = x4[lane];
    const float4* w4 = (const float4*)wmat;
    for (int r=wave; r<256; r+=4){
        float4 wv = w4[r*64+lane];
        float s = xv.x*wv.x + xv.y*wv.y + xv.z*wv.z + xv.w*wv.w;
#pragma unroll
        for (int off=32; off; off>>=1) s += __shfl_down(s,off,64);
        if (lane==0) dst[b*256+r] = tanhf(s + bias[r]);
    }
}

// ================= K_SCAN: single-WG persistent LSTM scan (i8 MFMA, Gp prefetch) =========
__global__ __launch_bounds__(512, 2) void k_scan(const int8_t* __restrict__ Wq,
                                                 const float* __restrict__ dqs,
                                                 const float* __restrict__ biasg,
                                                 const float* __restrict__ Gp,
                                                 const float* __restrict__ cxg,
                                                 const float* __restrict__ hxg,
                                                 const float* __restrict__ woutw,
                                                 float* __restrict__ out){
    const int tid  = threadIdx.x;
    const int wv   = tid >> 6, lane = tid & 63;
    const int q    = lane >> 4, n = lane & 15;

    __shared__ __align__(16) int8_t hxq[2][4*272];

    i32x4 bfrag[8][4];
#pragma unroll
    for (int ct=0; ct<8; ++ct)
#pragma unroll
        for (int kt=0; kt<4; ++kt)
            bfrag[ct][kt] = *(const i32x4*)(Wq +
                ((size_t)(((wv*8 + ct)*4 + kt)*4 + q)*16 + n)*16);

    const int ua = wv*32 + n, ub = ua + 16;
    float cxa = cxg[q*256 + ua], cxb = cxg[q*256 + ub];
    const float w0a = woutw[ua], w1a = woutw[256 + ua];
    const float w0b = woutw[ub], w1b = woutw[256 + ub];
    float dqa[4], dqb[4], bba[4], bbb[4];
#pragma unroll
    for (int g=0; g<4; ++g){
        dqa[g] = dqs[g*256 + ua];   dqb[g] = dqs[g*256 + ub];
        bba[g] = biasg[g*256 + ua]; bbb[g] = biasg[g*256 + ub];
    }

    {
        const int b0 = tid >> 7, u0 = tid & 127;
        hxq[0][b0*272 + u0]       = q8(hxg[b0*256 + u0]       * 127.0f);
        hxq[0][b0*272 + u0 + 128] = q8(hxg[b0*256 + u0 + 128] * 127.0f);
    }
    const float4* gp0 = (const float4*)(Gp + tid*8);
    float4 gA = gp0[0], gB = gp0[1];
    __syncthreads();

    for (int t=0; t<TT; ++t){
        const int tn = (t+1 < TT) ? t+1 : t;
        const float4* gpn = (const float4*)(Gp + (size_t)tn*4096 + tid*8);
        float4 nA = gpn[0], nB = gpn[1];

        const int8_t* hb = hxq[t & 1];
        i32x4 afr[4];
#pragma unroll
        for (int kt=0; kt<4; ++kt)
            afr[kt] = *(const i32x4*)(hb + (n >> 2)*272 + kt*64 + q*16);

        i32x4 acc[8];
#pragma unroll
        for (int ct=0; ct<8; ++ct){ acc[ct][0]=0; acc[ct][1]=0; acc[ct][2]=0; acc[ct][3]=0; }
#pragma unroll
        for (int ct=0; ct<8; ++ct)
#pragma unroll
            for (int kt=0; kt<4; ++kt)
                acc[ct] = __builtin_amdgcn_mfma_i32_16x16x64_i8(afr[kt], bfrag[ct][kt], acc[ct], 0, 0, 0);

        float gia = (float)acc[0][0]*dqa[0] + gA.x + bba[0];
        float gfa = (float)acc[2][0]*dqa[1] + gA.y + bba[1];
        float gga = (float)acc[4][0]*dqa[2] + gA.z + bba[2];
        float goa = (float)acc[6][0]*dqa[3] + gA.w + bba[3];
        float gib = (float)acc[1][0]*dqb[0] + gB.x + bbb[0];
        float gfb = (float)acc[3][0]*dqb[1] + gB.y + bbb[1];
        float ggb = (float)acc[5][0]*dqb[2] + gB.z + bbb[2];
        float gob = (float)acc[7][0]*dqb[3] + gB.w + bbb[3];

        float cna = fsigm(gfa)*cxa + fsigm(gia)*ftanh(gga);
        float hna = fsigm(goa)*ftanh(cna);
        float cnb = fsigm(gfb)*cxb + fsigm(gib)*ftanh(ggb);
        float hnb = fsigm(gob)*ftanh(cnb);
        cxa = cna; cxb = cnb;

        int8_t* hw = hxq[(t+1) & 1];
        hw[q*272 + ua] = q8(hna * 127.0f);
        hw[q*272 + ub] = q8(hnb * 127.0f);

        float p0 = hna*w0a + hnb*w0b;
        float p1 = hna*w1a + hnb*w1b;
#pragma unroll
        for (int off=1; off<16; off<<=1){
            p0 += __shfl_xor(p0, off, 64);
            p1 += __shfl_xor(p1, off, 64);
        }
        if (n == 0){
            atomicAdd(&out[t*8 + q*2 + 0], p0);
            atomicAdd(&out[t*8 + q*2 + 1], p1);
        }
        gA = nA; gB = nB;
        __syncthreads();
    }
}

extern "C" void kernel_launch(void* const* d_in, const int* in_sizes, int n_in,
                              void* d_out, int out_size, void* d_ws, size_t ws_size,
                              hipStream_t stream){
    const float* cam   = (const float*)d_in[0];
    const float* convw = (const float*)d_in[1];
    const float* convb = (const float*)d_in[2];
    const float* gamma = (const float*)d_in[3];
    const float* beta  = (const float*)d_in[4];
    const float* ihw   = (const float*)d_in[5];
    const float* ihb   = (const float*)d_in[6];
    const float* icw   = (const float*)d_in[7];
    const float* icb   = (const float*)d_in[8];
    const float* ww    = (const float*)d_in[9];
    const float* wb    = (const float*)d_in[10];
    const float* wattn = (const float*)d_in[11];
    // d_in[12] = wattn_b: unused (softmax is shift-invariant)
    const float* wih   = (const float*)d_in[13];
    const float* whh   = (const float*)d_in[14];
    const float* bih   = (const float*)d_in[15];
    const float* bhh   = (const float*)d_in[16];
    const float* woutw = (const float*)d_in[17];
    const float* woutb = (const float*)d_in[18];
    float* out = (float*)d_out;

    char* wsb = (char*)d_ws;
    size_t off = 0;
    auto alloc = [&](size_t bytes)->void*{
        void* p = wsb + off; off += (bytes + 255) & ~(size_t)255; return p;
    };
    unsigned short* y   = (unsigned short*)alloc((size_t)NF*FRAME*2);
    unsigned short* wr2 = (unsigned short*)alloc((size_t)589824*2);
    int8_t* Wq      = (int8_t*)alloc((size_t)262144);
    float* dqs      = (float*)alloc(1024*4);
    float* Sp       = (float*)alloc((size_t)NF*256*4);
    float* Sq       = (float*)alloc((size_t)NF*256*4);
    float* scale    = (float*)alloc(256*4);
    float* shift    = (float*)alloc(256*4);
    float* x0g      = (float*)alloc(1024*4);
    float* Gp       = (float*)alloc((size_t)TT*4096*4);
    float* biasg    = (float*)alloc(1024*4);
    float* hxg      = (float*)alloc(1024*4);
    float* cxg      = (float*)alloc(1024*4);

    hipLaunchKernelGGL(k_prep, dim3(S1_N + S2_N + 1), dim3(256), 0, stream,
                       convw, wih, whh, ww, wb, bih, bhh, woutb,
                       wr2, Wq, dqs, biasg, out);
    hipLaunchKernelGGL(k_conv2, dim3(4, NF), dim3(256), 0, stream, cam, wr2, convb, y, Sp, Sq);
    hipLaunchKernelGGL(k_bnfin, dim3(256), dim3(64), 0, stream, Sp, Sq, gamma, beta, scale, shift);
    hipLaunchKernelGGL(k_frame2, dim3(NF), dim3(256), 0, stream, y, scale, shift, wattn, wih, out, Gp, x0g);
    hipLaunchKernelGGL(k_init, dim3(8), dim3(256), 0, stream, x0g, ihw, ihb, icw, icb, hxg, cxg);
    hipLaunchKernelGGL(k_scan, dim3(1), dim3(512), 0, stream,
                       Wq, dqs, biasg, Gp, cxg, hxg, woutw, out);
}